// Round 4
// baseline (1289.408 us; speedup 1.0000x reference)
//
#include <hip/hip_runtime.h>
#include <math.h>

#define NA 2048
#define NB 1024
#define NC 1024
#define NN 4096
#define DD 128
#define HHH 4
#define CCC 32
#define E_AB 65536
#define E_AC 32768
#define E_CB 32768
#define E_HET 131072
#define E_TOT 135168
#define EPSV 1e-5f
#define SCALEV 0.17677669529663687f
#define KSLICES 16
#define KSLEN 256

static __device__ __forceinline__ unsigned short f2bf(float x) {
    union { float f; unsigned int u; } v; v.f = x;
    unsigned int r = v.u + 0x7FFF + ((v.u >> 16) & 1);
    return (unsigned short)(r >> 16);
}
static __device__ __forceinline__ float bf2f(unsigned short h) {
    union { unsigned int u; float f; } v; v.u = ((unsigned int)h) << 16;
    return v.f;
}

// ---------------- generic tiled GEMM: C[M,Nout] = A[M,K] @ B (+bias,+res,relu) ----------------
__global__ __launch_bounds__(256) void gemm_kernel(
    const float* __restrict__ A, const float* __restrict__ B,
    const float* __restrict__ bias, const float* __restrict__ res,
    float* __restrict__ C, int M, int Nout, int K, int transB, int relu)
{
    __shared__ float As[128][64];
    __shared__ float Bs[128][64];
    int t = threadIdx.x;
    int tx = t & 15, ty = t >> 4;
    int m0 = blockIdx.y * 64, n0 = blockIdx.x * 64;
    float acc[4][4] = {{0.f}};
    for (int k0 = 0; k0 < K; k0 += 128) {
        {
            int r = t & 63, kq = (t >> 6) << 2;
            const float* Ap = A + (size_t)(m0 + r) * K + k0 + kq;
            #pragma unroll
            for (int i = 0; i < 8; i++) {
                float4 v = *(const float4*)(Ap + i * 16);
                As[kq + i * 16 + 0][r] = v.x;
                As[kq + i * 16 + 1][r] = v.y;
                As[kq + i * 16 + 2][r] = v.z;
                As[kq + i * 16 + 3][r] = v.w;
            }
        }
        if (!transB) {
            int kk = t >> 4, c4 = (t & 15) << 2;
            #pragma unroll
            for (int i = 0; i < 8; i++) {
                float4 v = *(const float4*)(B + (size_t)(k0 + kk + i * 16) * Nout + n0 + c4);
                *(float4*)&Bs[kk + i * 16][c4] = v;
            }
        } else {
            int c = t & 63, kq = (t >> 6) << 2;
            const float* Bp = B + (size_t)(n0 + c) * K + k0 + kq;
            #pragma unroll
            for (int i = 0; i < 8; i++) {
                float4 v = *(const float4*)(Bp + i * 16);
                Bs[kq + i * 16 + 0][c] = v.x;
                Bs[kq + i * 16 + 1][c] = v.y;
                Bs[kq + i * 16 + 2][c] = v.z;
                Bs[kq + i * 16 + 3][c] = v.w;
            }
        }
        __syncthreads();
        #pragma unroll 8
        for (int k = 0; k < 128; k++) {
            float4 a = *(const float4*)&As[k][ty << 2];
            float4 b = *(const float4*)&Bs[k][tx << 2];
            acc[0][0] = fmaf(a.x, b.x, acc[0][0]);
            acc[0][1] = fmaf(a.x, b.y, acc[0][1]);
            acc[0][2] = fmaf(a.x, b.z, acc[0][2]);
            acc[0][3] = fmaf(a.x, b.w, acc[0][3]);
            acc[1][0] = fmaf(a.y, b.x, acc[1][0]);
            acc[1][1] = fmaf(a.y, b.y, acc[1][1]);
            acc[1][2] = fmaf(a.y, b.z, acc[1][2]);
            acc[1][3] = fmaf(a.y, b.w, acc[1][3]);
            acc[2][0] = fmaf(a.z, b.x, acc[2][0]);
            acc[2][1] = fmaf(a.z, b.y, acc[2][1]);
            acc[2][2] = fmaf(a.z, b.z, acc[2][2]);
            acc[2][3] = fmaf(a.z, b.w, acc[2][3]);
            acc[3][0] = fmaf(a.w, b.x, acc[3][0]);
            acc[3][1] = fmaf(a.w, b.y, acc[3][1]);
            acc[3][2] = fmaf(a.w, b.z, acc[3][2]);
            acc[3][3] = fmaf(a.w, b.w, acc[3][3]);
        }
        __syncthreads();
    }
    #pragma unroll
    for (int i = 0; i < 4; i++) {
        int r = m0 + (ty << 2) + i;
        #pragma unroll
        for (int j = 0; j < 4; j++) {
            int cc = n0 + (tx << 2) + j;
            float v = acc[i][j];
            if (bias) v += bias[cc];
            if (res) v += res[(size_t)r * Nout + cc];
            if (relu) v = fmaxf(v, 0.f);
            C[(size_t)r * Nout + cc] = v;
        }
    }
}

// ---------------- GAT attention scalar scores ----------------
__global__ __launch_bounds__(256) void att_scores(
    const float* __restrict__ xp, const float* __restrict__ att_src, const float* __restrict__ att_dst,
    float* __restrict__ asv, float* __restrict__ adv)
{
    int t = blockIdx.x * 256 + threadIdx.x;
    int n = t >> 2, hh = t & 3;
    const float* row = xp + (size_t)n * 128 + hh * 32;
    float s1 = 0.f, s2 = 0.f;
    #pragma unroll
    for (int c = 0; c < 32; c++) {
        float v = row[c];
        s1 = fmaf(v, att_src[hh * 32 + c], s1);
        s2 = fmaf(v, att_dst[hh * 32 + c], s2);
    }
    asv[t] = s1;
    adv[t] = s2;
}

// ---------------- CSR build ----------------
__global__ __launch_bounds__(256) void edge_hist(
    const int* __restrict__ ab_d, const int* __restrict__ ac_d, const int* __restrict__ cb_d,
    int* __restrict__ cnt)
{
    int e = blockIdx.x * 256 + threadIdx.x;
    int d;
    if (e < E_AB) d = ab_d[e] + NA;
    else if (e < E_AB + E_AC) d = ac_d[e - E_AB] + NA + NB;
    else if (e < E_HET) d = cb_d[e - E_AB - E_AC] + NA;
    else d = e - E_HET;
    atomicAdd(&cnt[d], 1);
}

__global__ __launch_bounds__(256) void scan_kernel(
    const int* __restrict__ cnt, int* __restrict__ rowptr, int* __restrict__ fill)
{
    __shared__ int sums[256];
    int t = threadIdx.x;
    int local[16];
    int s = 0;
    #pragma unroll
    for (int i = 0; i < 16; i++) { local[i] = s; s += cnt[t * 16 + i]; }
    sums[t] = s;
    __syncthreads();
    for (int d = 1; d < 256; d <<= 1) {
        int v = (t >= d) ? sums[t - d] : 0;
        __syncthreads();
        sums[t] += v;
        __syncthreads();
    }
    int base = sums[t] - s;
    #pragma unroll
    for (int i = 0; i < 16; i++) {
        int v = base + local[i];
        rowptr[t * 16 + i] = v;
        fill[t * 16 + i] = v;
    }
    if (t == 255) rowptr[NN] = sums[255];
}

__global__ __launch_bounds__(256) void edge_scatter(
    const int* __restrict__ ab_s, const int* __restrict__ ab_d,
    const int* __restrict__ ac_s, const int* __restrict__ ac_d,
    const int* __restrict__ cb_s, const int* __restrict__ cb_d,
    int* __restrict__ fill, int* __restrict__ csr)
{
    int e = blockIdx.x * 256 + threadIdx.x;
    int s, d;
    if (e < E_AB) { s = ab_s[e]; d = ab_d[e] + NA; }
    else if (e < E_AB + E_AC) { int i = e - E_AB; s = ac_s[i]; d = ac_d[i] + NA + NB; }
    else if (e < E_HET) { int i = e - E_AB - E_AC; s = cb_s[i] + NA + NB; d = cb_d[i] + NA; }
    else { s = e - E_HET; d = s; }
    int pos = atomicAdd(&fill[d], 1);
    csr[pos] = s;
}

// ---------------- GAT gather ----------------
__global__ __launch_bounds__(128) void gat_gather(
    const float* __restrict__ xp, const float* __restrict__ asv, const float* __restrict__ adv,
    const int* __restrict__ rowptr, const int* __restrict__ csr,
    const float* __restrict__ b_gat, const float* __restrict__ hres, float* __restrict__ y)
{
    int n = blockIdx.x;
    int t = threadIdx.x;
    int hh = t >> 5, c = t & 31;
    int beg = rowptr[n], end = rowptr[n + 1];
    float ad = adv[n * 4 + hh];
    float mh = -INFINITY;
    for (int j = beg; j < end; j++) {
        int s = csr[j];
        float e = asv[s * 4 + hh] + ad;
        e = (e > 0.f) ? e : 0.2f * e;
        mh = fmaxf(mh, e);
    }
    float denom = 0.f;
    for (int j = beg; j < end; j++) {
        int s = csr[j];
        float e = asv[s * 4 + hh] + ad;
        e = (e > 0.f) ? e : 0.2f * e;
        denom += __expf(e - mh);
    }
    float inv = 1.f / denom;
    float acc = 0.f;
    for (int j = beg; j < end; j++) {
        int s = csr[j];
        float e = asv[s * 4 + hh] + ad;
        e = (e > 0.f) ? e : 0.2f * e;
        acc = fmaf(__expf(e - mh) * inv, xp[(size_t)s * 128 + hh * 32 + c], acc);
    }
    y[(size_t)n * 128 + t] = acc + b_gat[t] + hres[(size_t)n * 128 + t];
}

// ---------------- BatchNorm stats ----------------
__global__ __launch_bounds__(256) void bn_stats(
    const float* __restrict__ x, float* __restrict__ mu, float* __restrict__ rstd)
{
    int c = blockIdx.x;
    int t = threadIdx.x;
    float s = 0.f, s2 = 0.f;
    for (int r = t; r < NN; r += 256) {
        float v = x[(size_t)r * 128 + c];
        s += v;
        s2 = fmaf(v, v, s2);
    }
    __shared__ float bs[256], bs2[256];
    bs[t] = s; bs2[t] = s2;
    __syncthreads();
    for (int d = 128; d; d >>= 1) {
        if (t < d) { bs[t] += bs[t + d]; bs2[t] += bs2[t + d]; }
        __syncthreads();
    }
    if (t == 0) {
        float m = bs[0] / (float)NN;
        float var = bs2[0] / (float)NN - m * m;
        mu[c] = m;
        rstd[c] = 1.f / sqrtf(var + EPSV);
    }
}

// ---------------- flash attention: LDS-tiled, double-buffered, 2 queries/thread ----------------
// grid: qb(8) x h(4) x kslice(16) = 512 blocks, 256 threads -> 2 blocks/CU.
// Partial O stored normalized by partial l, in bf16 (workspace budget).
__global__ __launch_bounds__(256, 2) void attn_kernel(
    const float* __restrict__ qkv, unsigned int* __restrict__ po,
    float* __restrict__ pm, float* __restrict__ pl)
{
    __shared__ float Ks[2][64][36];
    __shared__ float Vs[2][64][36];
    int bid = blockIdx.x;
    int ksl = bid & 15;
    int h = (bid >> 4) & 3;
    int qb = bid >> 6;
    int t = threadIdx.x;
    int q0 = qb * 512 + t;
    int q1 = q0 + 256;
    float qa[32], qz[32], acc0[32], acc1[32];
    {
        const float* p0 = qkv + (size_t)q0 * 384 + h * 32;
        const float* p1 = qkv + (size_t)q1 * 384 + h * 32;
        #pragma unroll
        for (int c = 0; c < 32; c++) {
            qa[c] = p0[c] * SCALEV;
            qz[c] = p1[c] * SCALEV;
            acc0[c] = 0.f; acc1[c] = 0.f;
        }
    }
    float m0 = -1e30f, m1 = -1e30f, l0 = 0.f, l1 = 0.f;
    int row = t >> 2, c8 = (t & 3) << 3;
    int kbase = ksl * KSLEN;
    float4 kA, kB, vA, vB;
    {
        const float* kr = qkv + (size_t)(kbase + row) * 384 + 128 + h * 32 + c8;
        kA = *(const float4*)kr; kB = *(const float4*)(kr + 4);
        vA = *(const float4*)(kr + 128); vB = *(const float4*)(kr + 132);
        *(float4*)&Ks[0][row][c8] = kA;
        *(float4*)&Ks[0][row][c8 + 4] = kB;
        *(float4*)&Vs[0][row][c8] = vA;
        *(float4*)&Vs[0][row][c8 + 4] = vB;
    }
    __syncthreads();
    #pragma unroll 1
    for (int tt = 0; tt < KSLEN / 64; tt++) {
        int buf = tt & 1;
        if (tt < KSLEN / 64 - 1) {  // issue next tile's global loads early
            const float* kr = qkv + (size_t)(kbase + (tt + 1) * 64 + row) * 384 + 128 + h * 32 + c8;
            kA = *(const float4*)kr; kB = *(const float4*)(kr + 4);
            vA = *(const float4*)(kr + 128); vB = *(const float4*)(kr + 132);
        }
        #pragma unroll 1
        for (int j0 = 0; j0 < 64; j0 += 8) {
            float s0[8], s1[8];
            #pragma unroll
            for (int j = 0; j < 8; j++) {
                const float* kw = &Ks[buf][j0 + j][0];
                float a0 = 0.f, a1 = 0.f, b0 = 0.f, b1 = 0.f;
                #pragma unroll
                for (int cq = 0; cq < 8; cq++) {
                    float4 kv = *(const float4*)(kw + cq * 4);
                    a0 = fmaf(qa[cq * 4 + 0], kv.x, a0);
                    a1 = fmaf(qa[cq * 4 + 1], kv.y, a1);
                    a0 = fmaf(qa[cq * 4 + 2], kv.z, a0);
                    a1 = fmaf(qa[cq * 4 + 3], kv.w, a1);
                    b0 = fmaf(qz[cq * 4 + 0], kv.x, b0);
                    b1 = fmaf(qz[cq * 4 + 1], kv.y, b1);
                    b0 = fmaf(qz[cq * 4 + 2], kv.z, b0);
                    b1 = fmaf(qz[cq * 4 + 3], kv.w, b1);
                }
                s0[j] = a0 + a1;
                s1[j] = b0 + b1;
            }
            float c0 = s0[0], c1 = s1[0];
            #pragma unroll
            for (int j = 1; j < 8; j++) { c0 = fmaxf(c0, s0[j]); c1 = fmaxf(c1, s1[j]); }
            if (c0 > m0) {
                float cr = __expf(m0 - c0);
                l0 *= cr;
                #pragma unroll
                for (int c = 0; c < 32; c++) acc0[c] *= cr;
                m0 = c0;
            }
            if (c1 > m1) {
                float cr = __expf(m1 - c1);
                l1 *= cr;
                #pragma unroll
                for (int c = 0; c < 32; c++) acc1[c] *= cr;
                m1 = c1;
            }
            float p0[8], p1[8];
            #pragma unroll
            for (int j = 0; j < 8; j++) {
                p0[j] = __expf(s0[j] - m0); l0 += p0[j];
                p1[j] = __expf(s1[j] - m1); l1 += p1[j];
            }
            #pragma unroll
            for (int j = 0; j < 8; j++) {
                const float* vw = &Vs[buf][j0 + j][0];
                #pragma unroll
                for (int cq = 0; cq < 8; cq++) {
                    float4 vv = *(const float4*)(vw + cq * 4);
                    acc0[cq * 4 + 0] = fmaf(p0[j], vv.x, acc0[cq * 4 + 0]);
                    acc0[cq * 4 + 1] = fmaf(p0[j], vv.y, acc0[cq * 4 + 1]);
                    acc0[cq * 4 + 2] = fmaf(p0[j], vv.z, acc0[cq * 4 + 2]);
                    acc0[cq * 4 + 3] = fmaf(p0[j], vv.w, acc0[cq * 4 + 3]);
                    acc1[cq * 4 + 0] = fmaf(p1[j], vv.x, acc1[cq * 4 + 0]);
                    acc1[cq * 4 + 1] = fmaf(p1[j], vv.y, acc1[cq * 4 + 1]);
                    acc1[cq * 4 + 2] = fmaf(p1[j], vv.z, acc1[cq * 4 + 2]);
                    acc1[cq * 4 + 3] = fmaf(p1[j], vv.w, acc1[cq * 4 + 3]);
                }
            }
        }
        if (tt < KSLEN / 64 - 1) {
            int nb = buf ^ 1;
            *(float4*)&Ks[nb][row][c8] = kA;
            *(float4*)&Ks[nb][row][c8 + 4] = kB;
            *(float4*)&Vs[nb][row][c8] = vA;
            *(float4*)&Vs[nb][row][c8 + 4] = vB;
        }
        __syncthreads();
    }
    int idx0 = (ksl * HHH + h) * NN + q0;
    int idx1 = idx0 + 256;
    pm[idx0] = m0; pl[idx0] = l0;
    pm[idx1] = m1; pl[idx1] = l1;
    float inv0 = 1.f / l0, inv1 = 1.f / l1;
    // po: bf16 normalized partial O, 2 values packed per u32 -> 16 u32 per (idx)
    #pragma unroll
    for (int j = 0; j < 16; j++) {
        unsigned int w0 = (unsigned int)f2bf(acc0[2 * j] * inv0) |
                          ((unsigned int)f2bf(acc0[2 * j + 1] * inv0) << 16);
        unsigned int w1 = (unsigned int)f2bf(acc1[2 * j] * inv1) |
                          ((unsigned int)f2bf(acc1[2 * j + 1] * inv1) << 16);
        po[(size_t)idx0 * 16 + j] = w0;
        po[(size_t)idx1 * 16 + j] = w1;
    }
}

__global__ __launch_bounds__(256) void attn_comb(
    const unsigned int* __restrict__ po, const float* __restrict__ pm, const float* __restrict__ pl,
    float* __restrict__ o_at)
{
    int idx = blockIdx.x * 256 + threadIdx.x;  // N*128
    int n = idx >> 7, hc = idx & 127, hh = hc >> 5, c = idx & 31;
    float M = -1e30f;
    #pragma unroll
    for (int s = 0; s < KSLICES; s++) M = fmaxf(M, pm[(s * HHH + hh) * NN + n]);
    float accv = 0.f, L = 0.f;
    #pragma unroll
    for (int s = 0; s < KSLICES; s++) {
        int id = (s * HHH + hh) * NN + n;
        float wgt = pl[id] * __expf(pm[id] - M);
        L += wgt;
        unsigned int w = po[(size_t)id * 16 + (c >> 1)];
        float pv = bf2f((unsigned short)((c & 1) ? (w >> 16) : (w & 0xFFFF)));
        accv = fmaf(wgt, pv, accv);
    }
    o_at[idx] = accv / L;
}

// ---------------- combine; final ----------------
__global__ __launch_bounds__(256) void combine_kernel(
    const float* __restrict__ y1, const float* __restrict__ y2,
    const float* __restrict__ stats,
    const float* __restrict__ g1, const float* __restrict__ be1,
    const float* __restrict__ g2, const float* __restrict__ be2,
    float* __restrict__ outp)
{
    int idx = blockIdx.x * 256 + threadIdx.x;
    int c = idx & 127;
    float v1 = (y1[idx] - stats[c]) * stats[128 + c] * g1[c] + be1[c];
    float v2 = (y2[idx] - stats[256 + c]) * stats[384 + c] * g2[c] + be2[c];
    outp[idx] = v1 + v2;
}

__global__ __launch_bounds__(256) void final_kernel(
    const float* __restrict__ out2, const float* __restrict__ stats,
    const float* __restrict__ g3, const float* __restrict__ be3,
    float* __restrict__ outv)
{
    int idx = blockIdx.x * 256 + threadIdx.x;
    int c = idx & 127;
    outv[idx] = (out2[idx] - stats[512 + c]) * stats[640 + c] * g3[c] + be3[c];
}

extern "C" void kernel_launch(void* const* d_in, const int* in_sizes, int n_in,
                              void* d_out, int out_size, void* d_ws, size_t ws_size,
                              hipStream_t stream)
{
    (void)in_sizes; (void)n_in; (void)out_size; (void)ws_size;
    const float* x_a   = (const float*)d_in[0];
    const float* x_b   = (const float*)d_in[1];
    const float* x_c   = (const float*)d_in[2];
    const int* ab_s    = (const int*)d_in[3];
    const int* ab_d    = (const int*)d_in[4];
    const int* ac_s    = (const int*)d_in[5];
    const int* ac_d    = (const int*)d_in[6];
    const int* cb_s    = (const int*)d_in[7];
    const int* cb_d    = (const int*)d_in[8];
    const float* W_in_a = (const float*)d_in[9];
    const float* b_in_a = (const float*)d_in[10];
    const float* W_in_b = (const float*)d_in[11];
    const float* b_in_b = (const float*)d_in[12];
    const float* W_in_c = (const float*)d_in[13];
    const float* b_in_c = (const float*)d_in[14];
    const float* W_gat  = (const float*)d_in[15];
    const float* att_src = (const float*)d_in[16];
    const float* att_dst = (const float*)d_in[17];
    const float* b_gat  = (const float*)d_in[18];
    const float* W_qkv  = (const float*)d_in[19];
    const float* b_qkv  = (const float*)d_in[20];
    const float* W_o    = (const float*)d_in[21];
    const float* b_o    = (const float*)d_in[22];
    const float* g1     = (const float*)d_in[23];
    const float* be1    = (const float*)d_in[24];
    const float* g2     = (const float*)d_in[25];
    const float* be2    = (const float*)d_in[26];
    const float* g3     = (const float*)d_in[27];
    const float* be3    = (const float*)d_in[28];
    const float* W_mlp1 = (const float*)d_in[29];
    const float* b_mlp1 = (const float*)d_in[30];
    const float* W_mlp2 = (const float*)d_in[31];
    const float* b_mlp2 = (const float*)d_in[32];

    float* ws   = (float*)d_ws;
    float* h    = ws + 0;          // 524288
    float* qkv  = ws + 524288;     // 1572864
    float* o_at = ws + 2097152;    // 524288
    float* y2   = ws + 2621440;    // 524288 (attn-time: pm/pl; later: o-proj+res)
    float* stats = ws + 3145728;   // 768
    float* R    = ws + 3146496;    // 4456448 floats (reused region)
    // attention-time views:
    unsigned int* po = (unsigned int*)R;  // 16*4*4096*16 u32 = 4194304 slots
    float* pm = y2;                // 262144
    float* pl = y2 + 262144;       // 262144
    // post-attention view of R:
    float* xp   = R + 0;           // 524288
    float* y1   = R + 524288;      // 524288
    float* outp = R + 1048576;     // 524288
    float* hid  = R + 1572864;     // 1048576
    float* out2 = R + 2621440;     // 524288
    float* asv  = R + 3145728;     // 16384
    float* adv  = R + 3162112;     // 16384
    int* cnt    = (int*)(R + 3178496);
    int* rowptr = cnt + 4096;      // 4104 incl pad
    int* fill   = rowptr + 4104;
    int* csr    = fill + 4096;     // E_TOT

    // ---- projections + qkv ----
    gemm_kernel<<<dim3(2, 32), 256, 0, stream>>>(x_a, W_in_a, b_in_a, nullptr, h, NA, 128, 128, 0, 0);
    gemm_kernel<<<dim3(2, 16), 256, 0, stream>>>(x_b, W_in_b, b_in_b, nullptr, h + (size_t)NA * 128, NB, 128, 128, 0, 0);
    gemm_kernel<<<dim3(2, 16), 256, 0, stream>>>(x_c, W_in_c, b_in_c, nullptr, h + (size_t)(NA + NB) * 128, NC, 128, 128, 0, 0);
    gemm_kernel<<<dim3(6, 64), 256, 0, stream>>>(h, W_qkv, b_qkv, nullptr, qkv, NN, 384, 128, 1, 0);
    // ---- global attention ----
    attn_kernel<<<8 * HHH * KSLICES, 256, 0, stream>>>(qkv, po, pm, pl);
    attn_comb<<<NN * 128 / 256, 256, 0, stream>>>(po, pm, pl, o_at);
    gemm_kernel<<<dim3(2, 64), 256, 0, stream>>>(o_at, W_o, b_o, h, y2, NN, 128, 128, 1, 0);
    bn_stats<<<128, 256, 0, stream>>>(y2, stats + 256, stats + 384);
    // ---- GAT branch (R reused) ----
    gemm_kernel<<<dim3(2, 64), 256, 0, stream>>>(h, W_gat, nullptr, nullptr, xp, NN, 128, 128, 0, 0);
    att_scores<<<64, 256, 0, stream>>>(xp, att_src, att_dst, asv, adv);
    hipMemsetAsync(cnt, 0, NN * sizeof(int), stream);
    edge_hist<<<E_TOT / 256, 256, 0, stream>>>(ab_d, ac_d, cb_d, cnt);
    scan_kernel<<<1, 256, 0, stream>>>(cnt, rowptr, fill);
    edge_scatter<<<E_TOT / 256, 256, 0, stream>>>(ab_s, ab_d, ac_s, ac_d, cb_s, cb_d, fill, csr);
    gat_gather<<<NN, 128, 0, stream>>>(xp, asv, adv, rowptr, csr, b_gat, h, y1);
    bn_stats<<<128, 256, 0, stream>>>(y1, stats + 0, stats + 128);
    // ---- combine + MLP ----
    combine_kernel<<<NN * 128 / 256, 256, 0, stream>>>(y1, y2, stats, g1, be1, g2, be2, outp);
    gemm_kernel<<<dim3(4, 64), 256, 0, stream>>>(outp, W_mlp1, b_mlp1, nullptr, hid, NN, 256, 128, 0, 1);
    gemm_kernel<<<dim3(2, 64), 256, 0, stream>>>(hid, W_mlp2, b_mlp2, outp, out2, NN, 128, 256, 0, 0);
    bn_stats<<<128, 256, 0, stream>>>(out2, stats + 512, stats + 640);
    final_kernel<<<NN * 128 / 256, 256, 0, stream>>>(out2, stats, g3, be3, (float*)d_out);
}

// Round 5
// 500.407 us; speedup vs baseline: 2.5767x; 2.5767x over previous
//
#include <hip/hip_runtime.h>
#include <math.h>

#define NA 2048
#define NB 1024
#define NC 1024
#define NN 4096
#define DD 128
#define HHH 4
#define CCC 32
#define E_AB 65536
#define E_AC 32768
#define E_CB 32768
#define E_HET 131072
#define E_TOT 135168
#define EPSV 1e-5f
#define SCALEV 0.17677669529663687f
#define KSLICES 16
#define KSLEN 256

static __device__ __forceinline__ unsigned short f2bf(float x) {
    union { float f; unsigned int u; } v; v.f = x;
    unsigned int r = v.u + 0x7FFF + ((v.u >> 16) & 1);
    return (unsigned short)(r >> 16);
}
static __device__ __forceinline__ float bf2f(unsigned short h) {
    union { unsigned int u; float f; } v; v.u = ((unsigned int)h) << 16;
    return v.f;
}

// ---------------- generic tiled GEMM: C[M,Nout] = A[M,K] @ B (+bias,+res,relu) ----------------
__global__ __launch_bounds__(256) void gemm_kernel(
    const float* __restrict__ A, const float* __restrict__ B,
    const float* __restrict__ bias, const float* __restrict__ res,
    float* __restrict__ C, int M, int Nout, int K, int transB, int relu)
{
    __shared__ float As[128][64];
    __shared__ float Bs[128][64];
    int t = threadIdx.x;
    int tx = t & 15, ty = t >> 4;
    int m0 = blockIdx.y * 64, n0 = blockIdx.x * 64;
    float acc[4][4] = {{0.f}};
    for (int k0 = 0; k0 < K; k0 += 128) {
        {
            int r = t & 63, kq = (t >> 6) << 2;
            const float* Ap = A + (size_t)(m0 + r) * K + k0 + kq;
            #pragma unroll
            for (int i = 0; i < 8; i++) {
                float4 v = *(const float4*)(Ap + i * 16);
                As[kq + i * 16 + 0][r] = v.x;
                As[kq + i * 16 + 1][r] = v.y;
                As[kq + i * 16 + 2][r] = v.z;
                As[kq + i * 16 + 3][r] = v.w;
            }
        }
        if (!transB) {
            int kk = t >> 4, c4 = (t & 15) << 2;
            #pragma unroll
            for (int i = 0; i < 8; i++) {
                float4 v = *(const float4*)(B + (size_t)(k0 + kk + i * 16) * Nout + n0 + c4);
                *(float4*)&Bs[kk + i * 16][c4] = v;
            }
        } else {
            int c = t & 63, kq = (t >> 6) << 2;
            const float* Bp = B + (size_t)(n0 + c) * K + k0 + kq;
            #pragma unroll
            for (int i = 0; i < 8; i++) {
                float4 v = *(const float4*)(Bp + i * 16);
                Bs[kq + i * 16 + 0][c] = v.x;
                Bs[kq + i * 16 + 1][c] = v.y;
                Bs[kq + i * 16 + 2][c] = v.z;
                Bs[kq + i * 16 + 3][c] = v.w;
            }
        }
        __syncthreads();
        #pragma unroll 8
        for (int k = 0; k < 128; k++) {
            float4 a = *(const float4*)&As[k][ty << 2];
            float4 b = *(const float4*)&Bs[k][tx << 2];
            acc[0][0] = fmaf(a.x, b.x, acc[0][0]);
            acc[0][1] = fmaf(a.x, b.y, acc[0][1]);
            acc[0][2] = fmaf(a.x, b.z, acc[0][2]);
            acc[0][3] = fmaf(a.x, b.w, acc[0][3]);
            acc[1][0] = fmaf(a.y, b.x, acc[1][0]);
            acc[1][1] = fmaf(a.y, b.y, acc[1][1]);
            acc[1][2] = fmaf(a.y, b.z, acc[1][2]);
            acc[1][3] = fmaf(a.y, b.w, acc[1][3]);
            acc[2][0] = fmaf(a.z, b.x, acc[2][0]);
            acc[2][1] = fmaf(a.z, b.y, acc[2][1]);
            acc[2][2] = fmaf(a.z, b.z, acc[2][2]);
            acc[2][3] = fmaf(a.z, b.w, acc[2][3]);
            acc[3][0] = fmaf(a.w, b.x, acc[3][0]);
            acc[3][1] = fmaf(a.w, b.y, acc[3][1]);
            acc[3][2] = fmaf(a.w, b.z, acc[3][2]);
            acc[3][3] = fmaf(a.w, b.w, acc[3][3]);
        }
        __syncthreads();
    }
    #pragma unroll
    for (int i = 0; i < 4; i++) {
        int r = m0 + (ty << 2) + i;
        #pragma unroll
        for (int j = 0; j < 4; j++) {
            int cc = n0 + (tx << 2) + j;
            float v = acc[i][j];
            if (bias) v += bias[cc];
            if (res) v += res[(size_t)r * Nout + cc];
            if (relu) v = fmaxf(v, 0.f);
            C[(size_t)r * Nout + cc] = v;
        }
    }
}

// ---------------- GAT attention scalar scores ----------------
__global__ __launch_bounds__(256) void att_scores(
    const float* __restrict__ xp, const float* __restrict__ att_src, const float* __restrict__ att_dst,
    float* __restrict__ asv, float* __restrict__ adv)
{
    int t = blockIdx.x * 256 + threadIdx.x;
    int n = t >> 2, hh = t & 3;
    const float* row = xp + (size_t)n * 128 + hh * 32;
    float s1 = 0.f, s2 = 0.f;
    #pragma unroll
    for (int c = 0; c < 32; c++) {
        float v = row[c];
        s1 = fmaf(v, att_src[hh * 32 + c], s1);
        s2 = fmaf(v, att_dst[hh * 32 + c], s2);
    }
    asv[t] = s1;
    adv[t] = s2;
}

// ---------------- CSR build ----------------
__global__ __launch_bounds__(256) void edge_hist(
    const int* __restrict__ ab_d, const int* __restrict__ ac_d, const int* __restrict__ cb_d,
    int* __restrict__ cnt)
{
    int e = blockIdx.x * 256 + threadIdx.x;
    int d;
    if (e < E_AB) d = ab_d[e] + NA;
    else if (e < E_AB + E_AC) d = ac_d[e - E_AB] + NA + NB;
    else if (e < E_HET) d = cb_d[e - E_AB - E_AC] + NA;
    else d = e - E_HET;
    atomicAdd(&cnt[d], 1);
}

__global__ __launch_bounds__(256) void scan_kernel(
    const int* __restrict__ cnt, int* __restrict__ rowptr, int* __restrict__ fill)
{
    __shared__ int sums[256];
    int t = threadIdx.x;
    int local[16];
    int s = 0;
    #pragma unroll
    for (int i = 0; i < 16; i++) { local[i] = s; s += cnt[t * 16 + i]; }
    sums[t] = s;
    __syncthreads();
    for (int d = 1; d < 256; d <<= 1) {
        int v = (t >= d) ? sums[t - d] : 0;
        __syncthreads();
        sums[t] += v;
        __syncthreads();
    }
    int base = sums[t] - s;
    #pragma unroll
    for (int i = 0; i < 16; i++) {
        int v = base + local[i];
        rowptr[t * 16 + i] = v;
        fill[t * 16 + i] = v;
    }
    if (t == 255) rowptr[NN] = sums[255];
}

__global__ __launch_bounds__(256) void edge_scatter(
    const int* __restrict__ ab_s, const int* __restrict__ ab_d,
    const int* __restrict__ ac_s, const int* __restrict__ ac_d,
    const int* __restrict__ cb_s, const int* __restrict__ cb_d,
    int* __restrict__ fill, int* __restrict__ csr)
{
    int e = blockIdx.x * 256 + threadIdx.x;
    int s, d;
    if (e < E_AB) { s = ab_s[e]; d = ab_d[e] + NA; }
    else if (e < E_AB + E_AC) { int i = e - E_AB; s = ac_s[i]; d = ac_d[i] + NA + NB; }
    else if (e < E_HET) { int i = e - E_AB - E_AC; s = cb_s[i] + NA + NB; d = cb_d[i] + NA; }
    else { s = e - E_HET; d = s; }
    int pos = atomicAdd(&fill[d], 1);
    csr[pos] = s;
}

// ---------------- GAT gather ----------------
__global__ __launch_bounds__(128) void gat_gather(
    const float* __restrict__ xp, const float* __restrict__ asv, const float* __restrict__ adv,
    const int* __restrict__ rowptr, const int* __restrict__ csr,
    const float* __restrict__ b_gat, const float* __restrict__ hres, float* __restrict__ y)
{
    int n = blockIdx.x;
    int t = threadIdx.x;
    int hh = t >> 5, c = t & 31;
    int beg = rowptr[n], end = rowptr[n + 1];
    float ad = adv[n * 4 + hh];
    float mh = -INFINITY;
    for (int j = beg; j < end; j++) {
        int s = csr[j];
        float e = asv[s * 4 + hh] + ad;
        e = (e > 0.f) ? e : 0.2f * e;
        mh = fmaxf(mh, e);
    }
    float denom = 0.f;
    for (int j = beg; j < end; j++) {
        int s = csr[j];
        float e = asv[s * 4 + hh] + ad;
        e = (e > 0.f) ? e : 0.2f * e;
        denom += __expf(e - mh);
    }
    float inv = 1.f / denom;
    float acc = 0.f;
    for (int j = beg; j < end; j++) {
        int s = csr[j];
        float e = asv[s * 4 + hh] + ad;
        e = (e > 0.f) ? e : 0.2f * e;
        acc = fmaf(__expf(e - mh) * inv, xp[(size_t)s * 128 + hh * 32 + c], acc);
    }
    y[(size_t)n * 128 + t] = acc + b_gat[t] + hres[(size_t)n * 128 + t];
}

// ---------------- BatchNorm stats ----------------
__global__ __launch_bounds__(256) void bn_stats(
    const float* __restrict__ x, float* __restrict__ mu, float* __restrict__ rstd)
{
    int c = blockIdx.x;
    int t = threadIdx.x;
    float s = 0.f, s2 = 0.f;
    for (int r = t; r < NN; r += 256) {
        float v = x[(size_t)r * 128 + c];
        s += v;
        s2 = fmaf(v, v, s2);
    }
    __shared__ float bs[256], bs2[256];
    bs[t] = s; bs2[t] = s2;
    __syncthreads();
    for (int d = 128; d; d >>= 1) {
        if (t < d) { bs[t] += bs[t + d]; bs2[t] += bs2[t + d]; }
        __syncthreads();
    }
    if (t == 0) {
        float m = bs[0] / (float)NN;
        float var = bs2[0] / (float)NN - m * m;
        mu[c] = m;
        rstd[c] = 1.f / sqrtf(var + EPSV);
    }
}

// ---------------- flash attention: LDS-tiled, double-buffered, 2 queries/thread ----------------
// grid: qb(8) x h(4) x kslice(16) = 512 blocks, 256 threads -> 2 blocks/CU.
// NO min-waves launch_bounds: ~220 VGPR naturally allows 2 waves/SIMD (cap at 256).
__global__ __launch_bounds__(256) void attn_kernel(
    const float* __restrict__ qkv, unsigned int* __restrict__ po,
    float* __restrict__ pm, float* __restrict__ pl)
{
    __shared__ float Ks[2][64][36];
    __shared__ float Vs[2][64][36];
    int bid = blockIdx.x;
    int ksl = bid & 15;
    int h = (bid >> 4) & 3;
    int qb = bid >> 6;
    int t = threadIdx.x;
    int q0 = qb * 512 + t;
    int q1 = q0 + 256;
    float qa[32], qz[32], acc0[32], acc1[32];
    {
        const float* p0 = qkv + (size_t)q0 * 384 + h * 32;
        const float* p1 = qkv + (size_t)q1 * 384 + h * 32;
        #pragma unroll
        for (int c = 0; c < 32; c++) {
            qa[c] = p0[c] * SCALEV;
            qz[c] = p1[c] * SCALEV;
            acc0[c] = 0.f; acc1[c] = 0.f;
        }
    }
    float m0 = -1e30f, m1 = -1e30f, l0 = 0.f, l1 = 0.f;
    int row = t >> 2, c8 = (t & 3) << 3;
    int kbase = ksl * KSLEN;
    float4 kA, kB, vA, vB;
    {
        const float* kr = qkv + (size_t)(kbase + row) * 384 + 128 + h * 32 + c8;
        kA = *(const float4*)kr; kB = *(const float4*)(kr + 4);
        vA = *(const float4*)(kr + 128); vB = *(const float4*)(kr + 132);
        *(float4*)&Ks[0][row][c8] = kA;
        *(float4*)&Ks[0][row][c8 + 4] = kB;
        *(float4*)&Vs[0][row][c8] = vA;
        *(float4*)&Vs[0][row][c8 + 4] = vB;
    }
    __syncthreads();
    #pragma unroll 1
    for (int tt = 0; tt < KSLEN / 64; tt++) {
        int buf = tt & 1;
        if (tt < KSLEN / 64 - 1) {  // issue next tile's global loads early
            const float* kr = qkv + (size_t)(kbase + (tt + 1) * 64 + row) * 384 + 128 + h * 32 + c8;
            kA = *(const float4*)kr; kB = *(const float4*)(kr + 4);
            vA = *(const float4*)(kr + 128); vB = *(const float4*)(kr + 132);
        }
        #pragma unroll 1
        for (int j0 = 0; j0 < 64; j0 += 8) {
            float s0[8], s1[8];
            #pragma unroll
            for (int j = 0; j < 8; j++) {
                const float* kw = &Ks[buf][j0 + j][0];
                float a0 = 0.f, a1 = 0.f, b0 = 0.f, b1 = 0.f;
                #pragma unroll
                for (int cq = 0; cq < 8; cq++) {
                    float4 kv = *(const float4*)(kw + cq * 4);
                    a0 = fmaf(qa[cq * 4 + 0], kv.x, a0);
                    a1 = fmaf(qa[cq * 4 + 1], kv.y, a1);
                    a0 = fmaf(qa[cq * 4 + 2], kv.z, a0);
                    a1 = fmaf(qa[cq * 4 + 3], kv.w, a1);
                    b0 = fmaf(qz[cq * 4 + 0], kv.x, b0);
                    b1 = fmaf(qz[cq * 4 + 1], kv.y, b1);
                    b0 = fmaf(qz[cq * 4 + 2], kv.z, b0);
                    b1 = fmaf(qz[cq * 4 + 3], kv.w, b1);
                }
                s0[j] = a0 + a1;
                s1[j] = b0 + b1;
            }
            float c0 = s0[0], c1 = s1[0];
            #pragma unroll
            for (int j = 1; j < 8; j++) { c0 = fmaxf(c0, s0[j]); c1 = fmaxf(c1, s1[j]); }
            if (c0 > m0) {
                float cr = __expf(m0 - c0);
                l0 *= cr;
                #pragma unroll
                for (int c = 0; c < 32; c++) acc0[c] *= cr;
                m0 = c0;
            }
            if (c1 > m1) {
                float cr = __expf(m1 - c1);
                l1 *= cr;
                #pragma unroll
                for (int c = 0; c < 32; c++) acc1[c] *= cr;
                m1 = c1;
            }
            float p0[8], p1[8];
            #pragma unroll
            for (int j = 0; j < 8; j++) {
                p0[j] = __expf(s0[j] - m0); l0 += p0[j];
                p1[j] = __expf(s1[j] - m1); l1 += p1[j];
            }
            #pragma unroll
            for (int j = 0; j < 8; j++) {
                const float* vw = &Vs[buf][j0 + j][0];
                #pragma unroll
                for (int cq = 0; cq < 8; cq++) {
                    float4 vv = *(const float4*)(vw + cq * 4);
                    acc0[cq * 4 + 0] = fmaf(p0[j], vv.x, acc0[cq * 4 + 0]);
                    acc0[cq * 4 + 1] = fmaf(p0[j], vv.y, acc0[cq * 4 + 1]);
                    acc0[cq * 4 + 2] = fmaf(p0[j], vv.z, acc0[cq * 4 + 2]);
                    acc0[cq * 4 + 3] = fmaf(p0[j], vv.w, acc0[cq * 4 + 3]);
                    acc1[cq * 4 + 0] = fmaf(p1[j], vv.x, acc1[cq * 4 + 0]);
                    acc1[cq * 4 + 1] = fmaf(p1[j], vv.y, acc1[cq * 4 + 1]);
                    acc1[cq * 4 + 2] = fmaf(p1[j], vv.z, acc1[cq * 4 + 2]);
                    acc1[cq * 4 + 3] = fmaf(p1[j], vv.w, acc1[cq * 4 + 3]);
                }
            }
        }
        if (tt < KSLEN / 64 - 1) {
            int nb = buf ^ 1;
            *(float4*)&Ks[nb][row][c8] = kA;
            *(float4*)&Ks[nb][row][c8 + 4] = kB;
            *(float4*)&Vs[nb][row][c8] = vA;
            *(float4*)&Vs[nb][row][c8 + 4] = vB;
        }
        __syncthreads();
    }
    int idx0 = (ksl * HHH + h) * NN + q0;
    int idx1 = idx0 + 256;
    pm[idx0] = m0; pl[idx0] = l0;
    pm[idx1] = m1; pl[idx1] = l1;
    float inv0 = 1.f / l0, inv1 = 1.f / l1;
    // po: bf16 normalized partial O, 2 values packed per u32 -> 16 u32 per (idx)
    #pragma unroll
    for (int j = 0; j < 16; j++) {
        unsigned int w0 = (unsigned int)f2bf(acc0[2 * j] * inv0) |
                          ((unsigned int)f2bf(acc0[2 * j + 1] * inv0) << 16);
        unsigned int w1 = (unsigned int)f2bf(acc1[2 * j] * inv1) |
                          ((unsigned int)f2bf(acc1[2 * j + 1] * inv1) << 16);
        po[(size_t)idx0 * 16 + j] = w0;
        po[(size_t)idx1 * 16 + j] = w1;
    }
}

__global__ __launch_bounds__(256) void attn_comb(
    const unsigned int* __restrict__ po, const float* __restrict__ pm, const float* __restrict__ pl,
    float* __restrict__ o_at)
{
    int idx = blockIdx.x * 256 + threadIdx.x;  // N*128
    int n = idx >> 7, hc = idx & 127, hh = hc >> 5, c = idx & 31;
    float M = -1e30f;
    #pragma unroll
    for (int s = 0; s < KSLICES; s++) M = fmaxf(M, pm[(s * HHH + hh) * NN + n]);
    float accv = 0.f, L = 0.f;
    #pragma unroll
    for (int s = 0; s < KSLICES; s++) {
        int id = (s * HHH + hh) * NN + n;
        float wgt = pl[id] * __expf(pm[id] - M);
        L += wgt;
        unsigned int w = po[(size_t)id * 16 + (c >> 1)];
        float pv = bf2f((unsigned short)((c & 1) ? (w >> 16) : (w & 0xFFFF)));
        accv = fmaf(wgt, pv, accv);
    }
    o_at[idx] = accv / L;
}

// ---------------- combine; final ----------------
__global__ __launch_bounds__(256) void combine_kernel(
    const float* __restrict__ y1, const float* __restrict__ y2,
    const float* __restrict__ stats,
    const float* __restrict__ g1, const float* __restrict__ be1,
    const float* __restrict__ g2, const float* __restrict__ be2,
    float* __restrict__ outp)
{
    int idx = blockIdx.x * 256 + threadIdx.x;
    int c = idx & 127;
    float v1 = (y1[idx] - stats[c]) * stats[128 + c] * g1[c] + be1[c];
    float v2 = (y2[idx] - stats[256 + c]) * stats[384 + c] * g2[c] + be2[c];
    outp[idx] = v1 + v2;
}

__global__ __launch_bounds__(256) void final_kernel(
    const float* __restrict__ out2, const float* __restrict__ stats,
    const float* __restrict__ g3, const float* __restrict__ be3,
    float* __restrict__ outv)
{
    int idx = blockIdx.x * 256 + threadIdx.x;
    int c = idx & 127;
    outv[idx] = (out2[idx] - stats[512 + c]) * stats[640 + c] * g3[c] + be3[c];
}

extern "C" void kernel_launch(void* const* d_in, const int* in_sizes, int n_in,
                              void* d_out, int out_size, void* d_ws, size_t ws_size,
                              hipStream_t stream)
{
    (void)in_sizes; (void)n_in; (void)out_size; (void)ws_size;
    const float* x_a   = (const float*)d_in[0];
    const float* x_b   = (const float*)d_in[1];
    const float* x_c   = (const float*)d_in[2];
    const int* ab_s    = (const int*)d_in[3];
    const int* ab_d    = (const int*)d_in[4];
    const int* ac_s    = (const int*)d_in[5];
    const int* ac_d    = (const int*)d_in[6];
    const int* cb_s    = (const int*)d_in[7];
    const int* cb_d    = (const int*)d_in[8];
    const float* W_in_a = (const float*)d_in[9];
    const float* b_in_a = (const float*)d_in[10];
    const float* W_in_b = (const float*)d_in[11];
    const float* b_in_b = (const float*)d_in[12];
    const float* W_in_c = (const float*)d_in[13];
    const float* b_in_c = (const float*)d_in[14];
    const float* W_gat  = (const float*)d_in[15];
    const float* att_src = (const float*)d_in[16];
    const float* att_dst = (const float*)d_in[17];
    const float* b_gat  = (const float*)d_in[18];
    const float* W_qkv  = (const float*)d_in[19];
    const float* b_qkv  = (const float*)d_in[20];
    const float* W_o    = (const float*)d_in[21];
    const float* b_o    = (const float*)d_in[22];
    const float* g1     = (const float*)d_in[23];
    const float* be1    = (const float*)d_in[24];
    const float* g2     = (const float*)d_in[25];
    const float* be2    = (const float*)d_in[26];
    const float* g3     = (const float*)d_in[27];
    const float* be3    = (const float*)d_in[28];
    const float* W_mlp1 = (const float*)d_in[29];
    const float* b_mlp1 = (const float*)d_in[30];
    const float* W_mlp2 = (const float*)d_in[31];
    const float* b_mlp2 = (const float*)d_in[32];

    float* ws   = (float*)d_ws;
    float* h    = ws + 0;          // 524288
    float* qkv  = ws + 524288;     // 1572864
    float* o_at = ws + 2097152;    // 524288
    float* y2   = ws + 2621440;    // 524288 (attn-time: pm/pl; later: o-proj+res)
    float* stats = ws + 3145728;   // 768
    float* R    = ws + 3146496;    // 4456448 floats (reused region)
    // attention-time views:
    unsigned int* po = (unsigned int*)R;  // 16*4*4096*16 u32 = 4194304 slots
    float* pm = y2;                // 262144
    float* pl = y2 + 262144;       // 262144
    // post-attention view of R:
    float* xp   = R + 0;           // 524288
    float* y1   = R + 524288;      // 524288
    float* outp = R + 1048576;     // 524288
    float* hid  = R + 1572864;     // 1048576
    float* out2 = R + 2621440;     // 524288
    float* asv  = R + 3145728;     // 16384
    float* adv  = R + 3162112;     // 16384
    int* cnt    = (int*)(R + 3178496);
    int* rowptr = cnt + 4096;      // 4104 incl pad
    int* fill   = rowptr + 4104;
    int* csr    = fill + 4096;     // E_TOT

    // ---- projections + qkv ----
    gemm_kernel<<<dim3(2, 32), 256, 0, stream>>>(x_a, W_in_a, b_in_a, nullptr, h, NA, 128, 128, 0, 0);
    gemm_kernel<<<dim3(2, 16), 256, 0, stream>>>(x_b, W_in_b, b_in_b, nullptr, h + (size_t)NA * 128, NB, 128, 128, 0, 0);
    gemm_kernel<<<dim3(2, 16), 256, 0, stream>>>(x_c, W_in_c, b_in_c, nullptr, h + (size_t)(NA + NB) * 128, NC, 128, 128, 0, 0);
    gemm_kernel<<<dim3(6, 64), 256, 0, stream>>>(h, W_qkv, b_qkv, nullptr, qkv, NN, 384, 128, 1, 0);
    // ---- global attention ----
    attn_kernel<<<8 * HHH * KSLICES, 256, 0, stream>>>(qkv, po, pm, pl);
    attn_comb<<<NN * 128 / 256, 256, 0, stream>>>(po, pm, pl, o_at);
    gemm_kernel<<<dim3(2, 64), 256, 0, stream>>>(o_at, W_o, b_o, h, y2, NN, 128, 128, 1, 0);
    bn_stats<<<128, 256, 0, stream>>>(y2, stats + 256, stats + 384);
    // ---- GAT branch (R reused) ----
    gemm_kernel<<<dim3(2, 64), 256, 0, stream>>>(h, W_gat, nullptr, nullptr, xp, NN, 128, 128, 0, 0);
    att_scores<<<64, 256, 0, stream>>>(xp, att_src, att_dst, asv, adv);
    hipMemsetAsync(cnt, 0, NN * sizeof(int), stream);
    edge_hist<<<E_TOT / 256, 256, 0, stream>>>(ab_d, ac_d, cb_d, cnt);
    scan_kernel<<<1, 256, 0, stream>>>(cnt, rowptr, fill);
    edge_scatter<<<E_TOT / 256, 256, 0, stream>>>(ab_s, ab_d, ac_s, ac_d, cb_s, cb_d, fill, csr);
    gat_gather<<<NN, 128, 0, stream>>>(xp, asv, adv, rowptr, csr, b_gat, h, y1);
    bn_stats<<<128, 256, 0, stream>>>(y1, stats + 0, stats + 128);
    // ---- combine + MLP ----
    combine_kernel<<<NN * 128 / 256, 256, 0, stream>>>(y1, y2, stats, g1, be1, g2, be2, outp);
    gemm_kernel<<<dim3(4, 64), 256, 0, stream>>>(outp, W_mlp1, b_mlp1, nullptr, hid, NN, 256, 128, 0, 1);
    gemm_kernel<<<dim3(2, 64), 256, 0, stream>>>(hid, W_mlp2, b_mlp2, outp, out2, NN, 128, 256, 0, 0);
    bn_stats<<<128, 256, 0, stream>>>(out2, stats + 512, stats + 640);
    final_kernel<<<NN * 128 / 256, 256, 0, stream>>>(out2, stats, g3, be3, (float*)d_out);
}

// Round 7
// 425.882 us; speedup vs baseline: 3.0276x; 1.1750x over previous
//
#include <hip/hip_runtime.h>
#include <math.h>

#define NA 2048
#define NB 1024
#define NC 1024
#define NN 4096
#define DD 128
#define HHH 4
#define CCC 32
#define E_AB 65536
#define E_AC 32768
#define E_CB 32768
#define E_HET 131072
#define E_TOT 135168
#define EPSV 1e-5f
#define SCALEV 0.17677669529663687f
#define KSLICES 16
#define KSLEN 256

static __device__ __forceinline__ unsigned short f2bf(float x) {
    union { float f; unsigned int u; } v; v.f = x;
    unsigned int r = v.u + 0x7FFF + ((v.u >> 16) & 1);
    return (unsigned short)(r >> 16);
}
static __device__ __forceinline__ float bf2f(unsigned short h) {
    union { unsigned int u; float f; } v; v.u = ((unsigned int)h) << 16;
    return v.f;
}

// ---------------- generic tiled GEMM: C[M,Nout] = A[M,K] @ B (+bias,+res,relu) ----------------
__global__ __launch_bounds__(256) void gemm_kernel(
    const float* __restrict__ A, const float* __restrict__ B,
    const float* __restrict__ bias, const float* __restrict__ res,
    float* __restrict__ C, int M, int Nout, int K, int transB, int relu)
{
    __shared__ float As[128][64];
    __shared__ float Bs[128][64];
    int t = threadIdx.x;
    int tx = t & 15, ty = t >> 4;
    int m0 = blockIdx.y * 64, n0 = blockIdx.x * 64;
    float acc[4][4] = {{0.f}};
    for (int k0 = 0; k0 < K; k0 += 128) {
        {
            int r = t & 63, kq = (t >> 6) << 2;
            const float* Ap = A + (size_t)(m0 + r) * K + k0 + kq;
            #pragma unroll
            for (int i = 0; i < 8; i++) {
                float4 v = *(const float4*)(Ap + i * 16);
                As[kq + i * 16 + 0][r] = v.x;
                As[kq + i * 16 + 1][r] = v.y;
                As[kq + i * 16 + 2][r] = v.z;
                As[kq + i * 16 + 3][r] = v.w;
            }
        }
        if (!transB) {
            int kk = t >> 4, c4 = (t & 15) << 2;
            #pragma unroll
            for (int i = 0; i < 8; i++) {
                float4 v = *(const float4*)(B + (size_t)(k0 + kk + i * 16) * Nout + n0 + c4);
                *(float4*)&Bs[kk + i * 16][c4] = v;
            }
        } else {
            int c = t & 63, kq = (t >> 6) << 2;
            const float* Bp = B + (size_t)(n0 + c) * K + k0 + kq;
            #pragma unroll
            for (int i = 0; i < 8; i++) {
                float4 v = *(const float4*)(Bp + i * 16);
                Bs[kq + i * 16 + 0][c] = v.x;
                Bs[kq + i * 16 + 1][c] = v.y;
                Bs[kq + i * 16 + 2][c] = v.z;
                Bs[kq + i * 16 + 3][c] = v.w;
            }
        }
        __syncthreads();
        #pragma unroll 8
        for (int k = 0; k < 128; k++) {
            float4 a = *(const float4*)&As[k][ty << 2];
            float4 b = *(const float4*)&Bs[k][tx << 2];
            acc[0][0] = fmaf(a.x, b.x, acc[0][0]);
            acc[0][1] = fmaf(a.x, b.y, acc[0][1]);
            acc[0][2] = fmaf(a.x, b.z, acc[0][2]);
            acc[0][3] = fmaf(a.x, b.w, acc[0][3]);
            acc[1][0] = fmaf(a.y, b.x, acc[1][0]);
            acc[1][1] = fmaf(a.y, b.y, acc[1][1]);
            acc[1][2] = fmaf(a.y, b.z, acc[1][2]);
            acc[1][3] = fmaf(a.y, b.w, acc[1][3]);
            acc[2][0] = fmaf(a.z, b.x, acc[2][0]);
            acc[2][1] = fmaf(a.z, b.y, acc[2][1]);
            acc[2][2] = fmaf(a.z, b.z, acc[2][2]);
            acc[2][3] = fmaf(a.z, b.w, acc[2][3]);
            acc[3][0] = fmaf(a.w, b.x, acc[3][0]);
            acc[3][1] = fmaf(a.w, b.y, acc[3][1]);
            acc[3][2] = fmaf(a.w, b.z, acc[3][2]);
            acc[3][3] = fmaf(a.w, b.w, acc[3][3]);
        }
        __syncthreads();
    }
    #pragma unroll
    for (int i = 0; i < 4; i++) {
        int r = m0 + (ty << 2) + i;
        #pragma unroll
        for (int j = 0; j < 4; j++) {
            int cc = n0 + (tx << 2) + j;
            float v = acc[i][j];
            if (bias) v += bias[cc];
            if (res) v += res[(size_t)r * Nout + cc];
            if (relu) v = fmaxf(v, 0.f);
            C[(size_t)r * Nout + cc] = v;
        }
    }
}

// ---------------- GAT attention scalar scores ----------------
__global__ __launch_bounds__(256) void att_scores(
    const float* __restrict__ xp, const float* __restrict__ att_src, const float* __restrict__ att_dst,
    float* __restrict__ asv, float* __restrict__ adv)
{
    int t = blockIdx.x * 256 + threadIdx.x;
    int n = t >> 2, hh = t & 3;
    const float* row = xp + (size_t)n * 128 + hh * 32;
    float s1 = 0.f, s2 = 0.f;
    #pragma unroll
    for (int c = 0; c < 32; c++) {
        float v = row[c];
        s1 = fmaf(v, att_src[hh * 32 + c], s1);
        s2 = fmaf(v, att_dst[hh * 32 + c], s2);
    }
    asv[t] = s1;
    adv[t] = s2;
}

// ---------------- CSR build ----------------
__global__ __launch_bounds__(256) void edge_hist(
    const int* __restrict__ ab_d, const int* __restrict__ ac_d, const int* __restrict__ cb_d,
    int* __restrict__ cnt)
{
    int e = blockIdx.x * 256 + threadIdx.x;
    int d;
    if (e < E_AB) d = ab_d[e] + NA;
    else if (e < E_AB + E_AC) d = ac_d[e - E_AB] + NA + NB;
    else if (e < E_HET) d = cb_d[e - E_AB - E_AC] + NA;
    else d = e - E_HET;
    atomicAdd(&cnt[d], 1);
}

__global__ __launch_bounds__(256) void scan_kernel(
    const int* __restrict__ cnt, int* __restrict__ rowptr, int* __restrict__ fill)
{
    __shared__ int sums[256];
    int t = threadIdx.x;
    int local[16];
    int s = 0;
    #pragma unroll
    for (int i = 0; i < 16; i++) { local[i] = s; s += cnt[t * 16 + i]; }
    sums[t] = s;
    __syncthreads();
    for (int d = 1; d < 256; d <<= 1) {
        int v = (t >= d) ? sums[t - d] : 0;
        __syncthreads();
        sums[t] += v;
        __syncthreads();
    }
    int base = sums[t] - s;
    #pragma unroll
    for (int i = 0; i < 16; i++) {
        int v = base + local[i];
        rowptr[t * 16 + i] = v;
        fill[t * 16 + i] = v;
    }
    if (t == 255) rowptr[NN] = sums[255];
}

__global__ __launch_bounds__(256) void edge_scatter(
    const int* __restrict__ ab_s, const int* __restrict__ ab_d,
    const int* __restrict__ ac_s, const int* __restrict__ ac_d,
    const int* __restrict__ cb_s, const int* __restrict__ cb_d,
    int* __restrict__ fill, int* __restrict__ csr)
{
    int e = blockIdx.x * 256 + threadIdx.x;
    int s, d;
    if (e < E_AB) { s = ab_s[e]; d = ab_d[e] + NA; }
    else if (e < E_AB + E_AC) { int i = e - E_AB; s = ac_s[i]; d = ac_d[i] + NA + NB; }
    else if (e < E_HET) { int i = e - E_AB - E_AC; s = cb_s[i] + NA + NB; d = cb_d[i] + NA; }
    else { s = e - E_HET; d = s; }
    int pos = atomicAdd(&fill[d], 1);
    csr[pos] = s;
}

// ---------------- GAT gather ----------------
__global__ __launch_bounds__(128) void gat_gather(
    const float* __restrict__ xp, const float* __restrict__ asv, const float* __restrict__ adv,
    const int* __restrict__ rowptr, const int* __restrict__ csr,
    const float* __restrict__ b_gat, const float* __restrict__ hres, float* __restrict__ y)
{
    int n = blockIdx.x;
    int t = threadIdx.x;
    int hh = t >> 5, c = t & 31;
    int beg = rowptr[n], end = rowptr[n + 1];
    float ad = adv[n * 4 + hh];
    float mh = -INFINITY;
    for (int j = beg; j < end; j++) {
        int s = csr[j];
        float e = asv[s * 4 + hh] + ad;
        e = (e > 0.f) ? e : 0.2f * e;
        mh = fmaxf(mh, e);
    }
    float denom = 0.f;
    for (int j = beg; j < end; j++) {
        int s = csr[j];
        float e = asv[s * 4 + hh] + ad;
        e = (e > 0.f) ? e : 0.2f * e;
        denom += __expf(e - mh);
    }
    float inv = 1.f / denom;
    float acc = 0.f;
    for (int j = beg; j < end; j++) {
        int s = csr[j];
        float e = asv[s * 4 + hh] + ad;
        e = (e > 0.f) ? e : 0.2f * e;
        acc = fmaf(__expf(e - mh) * inv, xp[(size_t)s * 128 + hh * 32 + c], acc);
    }
    y[(size_t)n * 128 + t] = acc + b_gat[t] + hres[(size_t)n * 128 + t];
}

// ---------------- BatchNorm stats ----------------
__global__ __launch_bounds__(256) void bn_stats(
    const float* __restrict__ x, float* __restrict__ mu, float* __restrict__ rstd)
{
    int c = blockIdx.x;
    int t = threadIdx.x;
    float s = 0.f, s2 = 0.f;
    for (int r = t; r < NN; r += 256) {
        float v = x[(size_t)r * 128 + c];
        s += v;
        s2 = fmaf(v, v, s2);
    }
    __shared__ float bs[256], bs2[256];
    bs[t] = s; bs2[t] = s2;
    __syncthreads();
    for (int d = 128; d; d >>= 1) {
        if (t < d) { bs[t] += bs[t + d]; bs2[t] += bs2[t + d]; }
        __syncthreads();
    }
    if (t == 0) {
        float m = bs[0] / (float)NN;
        float var = bs2[0] / (float)NN - m * m;
        mu[c] = m;
        rstd[c] = 1.f / sqrtf(var + EPSV);
    }
}

// ---------------- flash attention: LDS-tiled, double-buffered, 1 query/thread ----------------
// grid: qb(16) x h(4) x kslice(16) = 1024 blocks, 256 threads -> target 4 blocks/CU.
// Per-thread state ~110-125 VGPR (below the 128 occupancy step).
__global__ __launch_bounds__(256) void attn_kernel(
    const float* __restrict__ qkv, unsigned int* __restrict__ po,
    float* __restrict__ pm, float* __restrict__ pl)
{
    __shared__ float Ks[2][64][36];
    __shared__ float Vs[2][64][36];
    int bid = blockIdx.x;
    int ksl = bid & 15;
    int h = (bid >> 4) & 3;
    int qb = bid >> 6;
    int t = threadIdx.x;
    int q0 = qb * 256 + t;
    float qa[32], acc[32];
    {
        const float* p0 = qkv + (size_t)q0 * 384 + h * 32;
        #pragma unroll
        for (int c = 0; c < 32; c++) {
            qa[c] = p0[c] * SCALEV;
            acc[c] = 0.f;
        }
    }
    float m0 = -1e30f, l0 = 0.f;
    int row = t >> 2, c8 = (t & 3) << 3;
    int kbase = ksl * KSLEN;
    float4 kA, kB, vA, vB;
    {
        const float* kr = qkv + (size_t)(kbase + row) * 384 + 128 + h * 32 + c8;
        kA = *(const float4*)kr; kB = *(const float4*)(kr + 4);
        vA = *(const float4*)(kr + 128); vB = *(const float4*)(kr + 132);
        *(float4*)&Ks[0][row][c8] = kA;
        *(float4*)&Ks[0][row][c8 + 4] = kB;
        *(float4*)&Vs[0][row][c8] = vA;
        *(float4*)&Vs[0][row][c8 + 4] = vB;
    }
    __syncthreads();
    #pragma unroll 1
    for (int tt = 0; tt < KSLEN / 64; tt++) {
        int buf = tt & 1;
        if (tt < KSLEN / 64 - 1) {  // issue next tile's global loads early
            const float* kr = qkv + (size_t)(kbase + (tt + 1) * 64 + row) * 384 + 128 + h * 32 + c8;
            kA = *(const float4*)kr; kB = *(const float4*)(kr + 4);
            vA = *(const float4*)(kr + 128); vB = *(const float4*)(kr + 132);
        }
        #pragma unroll 1
        for (int j0 = 0; j0 < 64; j0 += 8) {
            float s0[8];
            #pragma unroll
            for (int j = 0; j < 8; j++) {
                const float* kw = &Ks[buf][j0 + j][0];
                float a0 = 0.f, a1 = 0.f;
                #pragma unroll
                for (int cq = 0; cq < 8; cq++) {
                    float4 kv = *(const float4*)(kw + cq * 4);
                    a0 = fmaf(qa[cq * 4 + 0], kv.x, a0);
                    a1 = fmaf(qa[cq * 4 + 1], kv.y, a1);
                    a0 = fmaf(qa[cq * 4 + 2], kv.z, a0);
                    a1 = fmaf(qa[cq * 4 + 3], kv.w, a1);
                }
                s0[j] = a0 + a1;
            }
            float c0 = s0[0];
            #pragma unroll
            for (int j = 1; j < 8; j++) c0 = fmaxf(c0, s0[j]);
            if (c0 > m0) {
                float cr = __expf(m0 - c0);
                l0 *= cr;
                #pragma unroll
                for (int c = 0; c < 32; c++) acc[c] *= cr;
                m0 = c0;
            }
            float p0[8];
            #pragma unroll
            for (int j = 0; j < 8; j++) {
                p0[j] = __expf(s0[j] - m0); l0 += p0[j];
            }
            #pragma unroll
            for (int j = 0; j < 8; j++) {
                const float* vw = &Vs[buf][j0 + j][0];
                #pragma unroll
                for (int cq = 0; cq < 8; cq++) {
                    float4 vv = *(const float4*)(vw + cq * 4);
                    acc[cq * 4 + 0] = fmaf(p0[j], vv.x, acc[cq * 4 + 0]);
                    acc[cq * 4 + 1] = fmaf(p0[j], vv.y, acc[cq * 4 + 1]);
                    acc[cq * 4 + 2] = fmaf(p0[j], vv.z, acc[cq * 4 + 2]);
                    acc[cq * 4 + 3] = fmaf(p0[j], vv.w, acc[cq * 4 + 3]);
                }
            }
        }
        if (tt < KSLEN / 64 - 1) {
            int nb = buf ^ 1;
            *(float4*)&Ks[nb][row][c8] = kA;
            *(float4*)&Ks[nb][row][c8 + 4] = kB;
            *(float4*)&Vs[nb][row][c8] = vA;
            *(float4*)&Vs[nb][row][c8 + 4] = vB;
        }
        __syncthreads();
    }
    int idx0 = (ksl * HHH + h) * NN + q0;
    pm[idx0] = m0; pl[idx0] = l0;
    float inv0 = 1.f / l0;
    // po: bf16 normalized partial O, 2 values packed per u32 -> 16 u32 per (idx)
    #pragma unroll
    for (int j = 0; j < 16; j++) {
        unsigned int w0 = (unsigned int)f2bf(acc[2 * j] * inv0) |
                          ((unsigned int)f2bf(acc[2 * j + 1] * inv0) << 16);
        po[(size_t)idx0 * 16 + j] = w0;
    }
}

__global__ __launch_bounds__(256) void attn_comb(
    const unsigned int* __restrict__ po, const float* __restrict__ pm, const float* __restrict__ pl,
    float* __restrict__ o_at)
{
    int idx = blockIdx.x * 256 + threadIdx.x;  // N*128
    int n = idx >> 7, hc = idx & 127, hh = hc >> 5, c = idx & 31;
    float M = -1e30f;
    #pragma unroll
    for (int s = 0; s < KSLICES; s++) M = fmaxf(M, pm[(s * HHH + hh) * NN + n]);
    float accv = 0.f, L = 0.f;
    #pragma unroll
    for (int s = 0; s < KSLICES; s++) {
        int id = (s * HHH + hh) * NN + n;
        float wgt = pl[id] * __expf(pm[id] - M);
        L += wgt;
        unsigned int w = po[(size_t)id * 16 + (c >> 1)];
        float pv = bf2f((unsigned short)((c & 1) ? (w >> 16) : (w & 0xFFFF)));
        accv = fmaf(wgt, pv, accv);
    }
    o_at[idx] = accv / L;
}

// ---------------- combine; final ----------------
__global__ __launch_bounds__(256) void combine_kernel(
    const float* __restrict__ y1, const float* __restrict__ y2,
    const float* __restrict__ stats,
    const float* __restrict__ g1, const float* __restrict__ be1,
    const float* __restrict__ g2, const float* __restrict__ be2,
    float* __restrict__ outp)
{
    int idx = blockIdx.x * 256 + threadIdx.x;
    int c = idx & 127;
    float v1 = (y1[idx] - stats[c]) * stats[128 + c] * g1[c] + be1[c];
    float v2 = (y2[idx] - stats[256 + c]) * stats[384 + c] * g2[c] + be2[c];
    outp[idx] = v1 + v2;
}

__global__ __launch_bounds__(256) void final_kernel(
    const float* __restrict__ out2, const float* __restrict__ stats,
    const float* __restrict__ g3, const float* __restrict__ be3,
    float* __restrict__ outv)
{
    int idx = blockIdx.x * 256 + threadIdx.x;
    int c = idx & 127;
    outv[idx] = (out2[idx] - stats[512 + c]) * stats[640 + c] * g3[c] + be3[c];
}

extern "C" void kernel_launch(void* const* d_in, const int* in_sizes, int n_in,
                              void* d_out, int out_size, void* d_ws, size_t ws_size,
                              hipStream_t stream)
{
    (void)in_sizes; (void)n_in; (void)out_size; (void)ws_size;
    const float* x_a   = (const float*)d_in[0];
    const float* x_b   = (const float*)d_in[1];
    const float* x_c   = (const float*)d_in[2];
    const int* ab_s    = (const int*)d_in[3];
    const int* ab_d    = (const int*)d_in[4];
    const int* ac_s    = (const int*)d_in[5];
    const int* ac_d    = (const int*)d_in[6];
    const int* cb_s    = (const int*)d_in[7];
    const int* cb_d    = (const int*)d_in[8];
    const float* W_in_a = (const float*)d_in[9];
    const float* b_in_a = (const float*)d_in[10];
    const float* W_in_b = (const float*)d_in[11];
    const float* b_in_b = (const float*)d_in[12];
    const float* W_in_c = (const float*)d_in[13];
    const float* b_in_c = (const float*)d_in[14];
    const float* W_gat  = (const float*)d_in[15];
    const float* att_src = (const float*)d_in[16];
    const float* att_dst = (const float*)d_in[17];
    const float* b_gat  = (const float*)d_in[18];
    const float* W_qkv  = (const float*)d_in[19];
    const float* b_qkv  = (const float*)d_in[20];
    const float* W_o    = (const float*)d_in[21];
    const float* b_o    = (const float*)d_in[22];
    const float* g1     = (const float*)d_in[23];
    const float* be1    = (const float*)d_in[24];
    const float* g2     = (const float*)d_in[25];
    const float* be2    = (const float*)d_in[26];
    const float* g3     = (const float*)d_in[27];
    const float* be3    = (const float*)d_in[28];
    const float* W_mlp1 = (const float*)d_in[29];
    const float* b_mlp1 = (const float*)d_in[30];
    const float* W_mlp2 = (const float*)d_in[31];
    const float* b_mlp2 = (const float*)d_in[32];

    float* ws   = (float*)d_ws;
    float* h    = ws + 0;          // 524288
    float* qkv  = ws + 524288;     // 1572864
    float* o_at = ws + 2097152;    // 524288
    float* y2   = ws + 2621440;    // 524288 (attn-time: pm/pl; later: o-proj+res)
    float* stats = ws + 3145728;   // 768
    float* R    = ws + 3146496;    // 4456448 floats (reused region)
    // attention-time views:
    unsigned int* po = (unsigned int*)R;  // 16*4*4096*16 u32 = 4194304 slots
    float* pm = y2;                // 262144
    float* pl = y2 + 262144;       // 262144
    // post-attention view of R:
    float* xp   = R + 0;           // 524288
    float* y1   = R + 524288;      // 524288
    float* outp = R + 1048576;     // 524288
    float* hid  = R + 1572864;     // 1048576
    float* out2 = R + 2621440;     // 524288
    float* asv  = R + 3145728;     // 16384
    float* adv  = R + 3162112;     // 16384
    int* cnt    = (int*)(R + 3178496);
    int* rowptr = cnt + 4096;      // 4104 incl pad
    int* fill   = rowptr + 4104;
    int* csr    = fill + 4096;     // E_TOT

    // ---- projections + qkv ----
    gemm_kernel<<<dim3(2, 32), 256, 0, stream>>>(x_a, W_in_a, b_in_a, nullptr, h, NA, 128, 128, 0, 0);
    gemm_kernel<<<dim3(2, 16), 256, 0, stream>>>(x_b, W_in_b, b_in_b, nullptr, h + (size_t)NA * 128, NB, 128, 128, 0, 0);
    gemm_kernel<<<dim3(2, 16), 256, 0, stream>>>(x_c, W_in_c, b_in_c, nullptr, h + (size_t)(NA + NB) * 128, NC, 128, 128, 0, 0);
    gemm_kernel<<<dim3(6, 64), 256, 0, stream>>>(h, W_qkv, b_qkv, nullptr, qkv, NN, 384, 128, 1, 0);
    // ---- global attention ----
    attn_kernel<<<16 * HHH * KSLICES, 256, 0, stream>>>(qkv, po, pm, pl);
    attn_comb<<<NN * 128 / 256, 256, 0, stream>>>(po, pm, pl, o_at);
    gemm_kernel<<<dim3(2, 64), 256, 0, stream>>>(o_at, W_o, b_o, h, y2, NN, 128, 128, 1, 0);
    bn_stats<<<128, 256, 0, stream>>>(y2, stats + 256, stats + 384);
    // ---- GAT branch (R reused) ----
    gemm_kernel<<<dim3(2, 64), 256, 0, stream>>>(h, W_gat, nullptr, nullptr, xp, NN, 128, 128, 0, 0);
    att_scores<<<64, 256, 0, stream>>>(xp, att_src, att_dst, asv, adv);
    hipMemsetAsync(cnt, 0, NN * sizeof(int), stream);
    edge_hist<<<E_TOT / 256, 256, 0, stream>>>(ab_d, ac_d, cb_d, cnt);
    scan_kernel<<<1, 256, 0, stream>>>(cnt, rowptr, fill);
    edge_scatter<<<E_TOT / 256, 256, 0, stream>>>(ab_s, ab_d, ac_s, ac_d, cb_s, cb_d, fill, csr);
    gat_gather<<<NN, 128, 0, stream>>>(xp, asv, adv, rowptr, csr, b_gat, h, y1);
    bn_stats<<<128, 256, 0, stream>>>(y1, stats + 0, stats + 128);
    // ---- combine + MLP ----
    combine_kernel<<<NN * 128 / 256, 256, 0, stream>>>(y1, y2, stats, g1, be1, g2, be2, outp);
    gemm_kernel<<<dim3(4, 64), 256, 0, stream>>>(outp, W_mlp1, b_mlp1, nullptr, hid, NN, 256, 128, 0, 1);
    gemm_kernel<<<dim3(2, 64), 256, 0, stream>>>(hid, W_mlp2, b_mlp2, outp, out2, NN, 128, 256, 0, 0);
    bn_stats<<<128, 256, 0, stream>>>(out2, stats + 512, stats + 640);
    final_kernel<<<NN * 128 / 256, 256, 0, stream>>>(out2, stats, g3, be3, (float*)d_out);
}

// Round 8
// 333.178 us; speedup vs baseline: 3.8700x; 1.2782x over previous
//
#include <hip/hip_runtime.h>
#include <math.h>

#define NA 2048
#define NB 1024
#define NC 1024
#define NN 4096
#define DD 128
#define HHH 4
#define CCC 32
#define E_AB 65536
#define E_AC 32768
#define E_CB 32768
#define E_HET 131072
#define E_TOT 135168
#define EPSV 1e-5f
#define SCALEV 0.17677669529663687f
#define KSLICES 4
#define KSLEN 1024

typedef __attribute__((ext_vector_type(8))) short bf16x8;
typedef __attribute__((ext_vector_type(4))) float f32x4;

static __device__ __forceinline__ unsigned int cvtpk(float a, float b) {
    unsigned int r;
    asm("v_cvt_pk_bf16_f32 %0, %1, %2" : "=v"(r) : "v"(a), "v"(b));
    return r;
}

// ---------------- generic tiled GEMM: C[M,Nout] = A[M,K] @ B (+bias,+res,relu) ----------------
__global__ __launch_bounds__(256) void gemm_kernel(
    const float* __restrict__ A, const float* __restrict__ B,
    const float* __restrict__ bias, const float* __restrict__ res,
    float* __restrict__ C, int M, int Nout, int K, int transB, int relu)
{
    __shared__ float As[128][64];
    __shared__ float Bs[128][64];
    int t = threadIdx.x;
    int tx = t & 15, ty = t >> 4;
    int m0 = blockIdx.y * 64, n0 = blockIdx.x * 64;
    float acc[4][4] = {{0.f}};
    for (int k0 = 0; k0 < K; k0 += 128) {
        {
            int r = t & 63, kq = (t >> 6) << 2;
            const float* Ap = A + (size_t)(m0 + r) * K + k0 + kq;
            #pragma unroll
            for (int i = 0; i < 8; i++) {
                float4 v = *(const float4*)(Ap + i * 16);
                As[kq + i * 16 + 0][r] = v.x;
                As[kq + i * 16 + 1][r] = v.y;
                As[kq + i * 16 + 2][r] = v.z;
                As[kq + i * 16 + 3][r] = v.w;
            }
        }
        if (!transB) {
            int kk = t >> 4, c4 = (t & 15) << 2;
            #pragma unroll
            for (int i = 0; i < 8; i++) {
                float4 v = *(const float4*)(B + (size_t)(k0 + kk + i * 16) * Nout + n0 + c4);
                *(float4*)&Bs[kk + i * 16][c4] = v;
            }
        } else {
            int c = t & 63, kq = (t >> 6) << 2;
            const float* Bp = B + (size_t)(n0 + c) * K + k0 + kq;
            #pragma unroll
            for (int i = 0; i < 8; i++) {
                float4 v = *(const float4*)(Bp + i * 16);
                Bs[kq + i * 16 + 0][c] = v.x;
                Bs[kq + i * 16 + 1][c] = v.y;
                Bs[kq + i * 16 + 2][c] = v.z;
                Bs[kq + i * 16 + 3][c] = v.w;
            }
        }
        __syncthreads();
        #pragma unroll 8
        for (int k = 0; k < 128; k++) {
            float4 a = *(const float4*)&As[k][ty << 2];
            float4 b = *(const float4*)&Bs[k][tx << 2];
            acc[0][0] = fmaf(a.x, b.x, acc[0][0]);
            acc[0][1] = fmaf(a.x, b.y, acc[0][1]);
            acc[0][2] = fmaf(a.x, b.z, acc[0][2]);
            acc[0][3] = fmaf(a.x, b.w, acc[0][3]);
            acc[1][0] = fmaf(a.y, b.x, acc[1][0]);
            acc[1][1] = fmaf(a.y, b.y, acc[1][1]);
            acc[1][2] = fmaf(a.y, b.z, acc[1][2]);
            acc[1][3] = fmaf(a.y, b.w, acc[1][3]);
            acc[2][0] = fmaf(a.z, b.x, acc[2][0]);
            acc[2][1] = fmaf(a.z, b.y, acc[2][1]);
            acc[2][2] = fmaf(a.z, b.z, acc[2][2]);
            acc[2][3] = fmaf(a.z, b.w, acc[2][3]);
            acc[3][0] = fmaf(a.w, b.x, acc[3][0]);
            acc[3][1] = fmaf(a.w, b.y, acc[3][1]);
            acc[3][2] = fmaf(a.w, b.z, acc[3][2]);
            acc[3][3] = fmaf(a.w, b.w, acc[3][3]);
        }
        __syncthreads();
    }
    #pragma unroll
    for (int i = 0; i < 4; i++) {
        int r = m0 + (ty << 2) + i;
        #pragma unroll
        for (int j = 0; j < 4; j++) {
            int cc = n0 + (tx << 2) + j;
            float v = acc[i][j];
            if (bias) v += bias[cc];
            if (res) v += res[(size_t)r * Nout + cc];
            if (relu) v = fmaxf(v, 0.f);
            C[(size_t)r * Nout + cc] = v;
        }
    }
}

// ---------------- GAT attention scalar scores ----------------
__global__ __launch_bounds__(256) void att_scores(
    const float* __restrict__ xp, const float* __restrict__ att_src, const float* __restrict__ att_dst,
    float* __restrict__ asv, float* __restrict__ adv)
{
    int t = blockIdx.x * 256 + threadIdx.x;
    int n = t >> 2, hh = t & 3;
    const float* row = xp + (size_t)n * 128 + hh * 32;
    float s1 = 0.f, s2 = 0.f;
    #pragma unroll
    for (int c = 0; c < 32; c++) {
        float v = row[c];
        s1 = fmaf(v, att_src[hh * 32 + c], s1);
        s2 = fmaf(v, att_dst[hh * 32 + c], s2);
    }
    asv[t] = s1;
    adv[t] = s2;
}

// ---------------- CSR build ----------------
__global__ __launch_bounds__(256) void edge_hist(
    const int* __restrict__ ab_d, const int* __restrict__ ac_d, const int* __restrict__ cb_d,
    int* __restrict__ cnt)
{
    int e = blockIdx.x * 256 + threadIdx.x;
    int d;
    if (e < E_AB) d = ab_d[e] + NA;
    else if (e < E_AB + E_AC) d = ac_d[e - E_AB] + NA + NB;
    else if (e < E_HET) d = cb_d[e - E_AB - E_AC] + NA;
    else d = e - E_HET;
    atomicAdd(&cnt[d], 1);
}

__global__ __launch_bounds__(256) void scan_kernel(
    const int* __restrict__ cnt, int* __restrict__ rowptr, int* __restrict__ fill)
{
    __shared__ int sums[256];
    int t = threadIdx.x;
    int local[16];
    int s = 0;
    #pragma unroll
    for (int i = 0; i < 16; i++) { local[i] = s; s += cnt[t * 16 + i]; }
    sums[t] = s;
    __syncthreads();
    for (int d = 1; d < 256; d <<= 1) {
        int v = (t >= d) ? sums[t - d] : 0;
        __syncthreads();
        sums[t] += v;
        __syncthreads();
    }
    int base = sums[t] - s;
    #pragma unroll
    for (int i = 0; i < 16; i++) {
        int v = base + local[i];
        rowptr[t * 16 + i] = v;
        fill[t * 16 + i] = v;
    }
    if (t == 255) rowptr[NN] = sums[255];
}

__global__ __launch_bounds__(256) void edge_scatter(
    const int* __restrict__ ab_s, const int* __restrict__ ab_d,
    const int* __restrict__ ac_s, const int* __restrict__ ac_d,
    const int* __restrict__ cb_s, const int* __restrict__ cb_d,
    int* __restrict__ fill, int* __restrict__ csr)
{
    int e = blockIdx.x * 256 + threadIdx.x;
    int s, d;
    if (e < E_AB) { s = ab_s[e]; d = ab_d[e] + NA; }
    else if (e < E_AB + E_AC) { int i = e - E_AB; s = ac_s[i]; d = ac_d[i] + NA + NB; }
    else if (e < E_HET) { int i = e - E_AB - E_AC; s = cb_s[i] + NA + NB; d = cb_d[i] + NA; }
    else { s = e - E_HET; d = s; }
    int pos = atomicAdd(&fill[d], 1);
    csr[pos] = s;
}

// ---------------- GAT gather ----------------
__global__ __launch_bounds__(128) void gat_gather(
    const float* __restrict__ xp, const float* __restrict__ asv, const float* __restrict__ adv,
    const int* __restrict__ rowptr, const int* __restrict__ csr,
    const float* __restrict__ b_gat, const float* __restrict__ hres, float* __restrict__ y)
{
    int n = blockIdx.x;
    int t = threadIdx.x;
    int hh = t >> 5, c = t & 31;
    int beg = rowptr[n], end = rowptr[n + 1];
    float ad = adv[n * 4 + hh];
    float mh = -INFINITY;
    for (int j = beg; j < end; j++) {
        int s = csr[j];
        float e = asv[s * 4 + hh] + ad;
        e = (e > 0.f) ? e : 0.2f * e;
        mh = fmaxf(mh, e);
    }
    float denom = 0.f;
    for (int j = beg; j < end; j++) {
        int s = csr[j];
        float e = asv[s * 4 + hh] + ad;
        e = (e > 0.f) ? e : 0.2f * e;
        denom += __expf(e - mh);
    }
    float inv = 1.f / denom;
    float acc = 0.f;
    for (int j = beg; j < end; j++) {
        int s = csr[j];
        float e = asv[s * 4 + hh] + ad;
        e = (e > 0.f) ? e : 0.2f * e;
        acc = fmaf(__expf(e - mh) * inv, xp[(size_t)s * 128 + hh * 32 + c], acc);
    }
    y[(size_t)n * 128 + t] = acc + b_gat[t] + hres[(size_t)n * 128 + t];
}

// ---------------- BatchNorm stats ----------------
__global__ __launch_bounds__(256) void bn_stats(
    const float* __restrict__ x, float* __restrict__ mu, float* __restrict__ rstd)
{
    int c = blockIdx.x;
    int t = threadIdx.x;
    float s = 0.f, s2 = 0.f;
    for (int r = t; r < NN; r += 256) {
        float v = x[(size_t)r * 128 + c];
        s += v;
        s2 = fmaf(v, v, s2);
    }
    __shared__ float bs[256], bs2[256];
    bs[t] = s; bs2[t] = s2;
    __syncthreads();
    for (int d = 128; d; d >>= 1) {
        if (t < d) { bs[t] += bs[t + d]; bs2[t] += bs2[t + d]; }
        __syncthreads();
    }
    if (t == 0) {
        float m = bs[0] / (float)NN;
        float var = bs2[0] / (float)NN - m * m;
        mu[c] = m;
        rstd[c] = 1.f / sqrtf(var + EPSV);
    }
}

// ---------------- MFMA flash attention ----------------
// 1-wave (64t) blocks; each owns 16 q-rows x 1 head x 1024-key slice. No barriers.
// grid: ksl(4) x h(4) x qb(256) = 4096 blocks.
// mfma_f32_16x16x32_bf16: C/D: col=lane&15, row=(lane>>4)*4+reg (verified layout).
// A: row=lane&15, k=(lane>>4)*8+e ; B: col=lane&15, k=(lane>>4)*8+e. Any consistent
// k-permutation across A and B cancels in the dot product.
__global__ __launch_bounds__(64) void attn_kernel(
    const float* __restrict__ qkv, float* __restrict__ po,
    float* __restrict__ pm, float* __restrict__ pl)
{
    __shared__ float P[16][68];  // P[q][key-in-tile], pad 68 (16B-aligned rows)
    int bid = blockIdx.x;
    int ksl = bid & 3;
    int h = (bid >> 2) & 3;
    int qb = bid >> 4;
    int l = threadIdx.x;
    int lg = l >> 4, lc = l & 15;
    int q0 = qb * 16;
    f32x4 zero = {0.f, 0.f, 0.f, 0.f};
    // Q-frag: lane holds Q[q0+lc][c = lg*8+e] * SCALE (bf16)
    bf16x8 qf;
    {
        const float* qp = qkv + (size_t)(q0 + lc) * 384 + h * 32 + lg * 8;
        float4 a = *(const float4*)qp;
        float4 b = *(const float4*)(qp + 4);
        union { unsigned int u[4]; bf16x8 v; } t;
        t.u[0] = cvtpk(a.x * SCALEV, a.y * SCALEV);
        t.u[1] = cvtpk(a.z * SCALEV, a.w * SCALEV);
        t.u[2] = cvtpk(b.x * SCALEV, b.y * SCALEV);
        t.u[3] = cvtpk(b.z * SCALEV, b.w * SCALEV);
        qf = t.v;
    }
    f32x4 o0 = zero, o1 = zero;                      // O[q=lg*4+r][lc], [lc+16]
    float mx[4] = {-1e30f, -1e30f, -1e30f, -1e30f};  // per r (q-row)
    float ls[4] = {0.f, 0.f, 0.f, 0.f};
    int kbeg = ksl * KSLEN;
    #pragma unroll 1
    for (int kt = kbeg; kt < kbeg + KSLEN; kt += 64) {
        // ---- QK^T: S[16q x 64k] in 4 subtiles ----
        f32x4 s[4];
        #pragma unroll
        for (int sub = 0; sub < 4; sub++) {
            const float* kp = qkv + (size_t)(kt + sub * 16 + lc) * 384 + 128 + h * 32 + lg * 8;
            float4 a = *(const float4*)kp;
            float4 b = *(const float4*)(kp + 4);
            union { unsigned int u[4]; bf16x8 v; } t;
            t.u[0] = cvtpk(a.x, a.y); t.u[1] = cvtpk(a.z, a.w);
            t.u[2] = cvtpk(b.x, b.y); t.u[3] = cvtpk(b.z, b.w);
            s[sub] = __builtin_amdgcn_mfma_f32_16x16x32_bf16(qf, t.v, zero, 0, 0, 0);
        }
        // ---- issue V loads early (latency hides under softmax) ----
        // B-frag V: lane needs V[kt + ks*32 + lg*8 + e][ct*16 + lc]
        float vv[2][2][8];
        #pragma unroll
        for (int ks = 0; ks < 2; ks++) {
            #pragma unroll
            for (int ct = 0; ct < 2; ct++) {
                const float* vb = qkv + (size_t)(kt + ks * 32 + lg * 8) * 384 + 256 + h * 32 + ct * 16 + lc;
                #pragma unroll
                for (int e = 0; e < 8; e++) vv[ks][ct][e] = vb[(size_t)e * 384];
            }
        }
        // ---- online softmax (per q-row r; 16-lane group shfl reduce) ----
        float p_[4][4];  // [sub][r]
        #pragma unroll
        for (int r = 0; r < 4; r++) {
            float tm = fmaxf(fmaxf(s[0][r], s[1][r]), fmaxf(s[2][r], s[3][r]));
            tm = fmaxf(tm, __shfl_xor(tm, 1));
            tm = fmaxf(tm, __shfl_xor(tm, 2));
            tm = fmaxf(tm, __shfl_xor(tm, 4));
            tm = fmaxf(tm, __shfl_xor(tm, 8));
            if (tm > mx[r]) {
                float cr = __expf(mx[r] - tm);
                ls[r] *= cr;
                o0[r] *= cr;
                o1[r] *= cr;
                mx[r] = tm;
            }
            float rs = 0.f;
            #pragma unroll
            for (int sub = 0; sub < 4; sub++) {
                p_[sub][r] = __expf(s[sub][r] - mx[r]);
                rs += p_[sub][r];
            }
            rs += __shfl_xor(rs, 1);
            rs += __shfl_xor(rs, 2);
            rs += __shfl_xor(rs, 4);
            rs += __shfl_xor(rs, 8);
            ls[r] += rs;
        }
        // ---- P -> LDS (D-layout scatter; same-wave, no barrier) ----
        #pragma unroll
        for (int sub = 0; sub < 4; sub++) {
            #pragma unroll
            for (int r = 0; r < 4; r++)
                P[lg * 4 + r][sub * 16 + lc] = p_[sub][r];
        }
        // ---- A-frag P: lane reads P[lc][ks*32 + lg*8 + e] ----
        bf16x8 pa[2];
        #pragma unroll
        for (int ks = 0; ks < 2; ks++) {
            const float* pr = &P[lc][ks * 32 + lg * 8];
            float4 a = *(const float4*)pr;
            float4 b = *(const float4*)(pr + 4);
            union { unsigned int u[4]; bf16x8 v; } t;
            t.u[0] = cvtpk(a.x, a.y); t.u[1] = cvtpk(a.z, a.w);
            t.u[2] = cvtpk(b.x, b.y); t.u[3] = cvtpk(b.z, b.w);
            pa[ks] = t.v;
        }
        // ---- PV: O += P.V over 2 k-steps x 2 c-tiles ----
        #pragma unroll
        for (int ks = 0; ks < 2; ks++) {
            union { unsigned int u[4]; bf16x8 v; } t0, t1;
            t0.u[0] = cvtpk(vv[ks][0][0], vv[ks][0][1]);
            t0.u[1] = cvtpk(vv[ks][0][2], vv[ks][0][3]);
            t0.u[2] = cvtpk(vv[ks][0][4], vv[ks][0][5]);
            t0.u[3] = cvtpk(vv[ks][0][6], vv[ks][0][7]);
            t1.u[0] = cvtpk(vv[ks][1][0], vv[ks][1][1]);
            t1.u[1] = cvtpk(vv[ks][1][2], vv[ks][1][3]);
            t1.u[2] = cvtpk(vv[ks][1][4], vv[ks][1][5]);
            t1.u[3] = cvtpk(vv[ks][1][6], vv[ks][1][7]);
            o0 = __builtin_amdgcn_mfma_f32_16x16x32_bf16(pa[ks], t0.v, o0, 0, 0, 0);
            o1 = __builtin_amdgcn_mfma_f32_16x16x32_bf16(pa[ks], t1.v, o1, 0, 0, 0);
        }
    }
    // ---- write unnormalized partials (fp32) ----
    int base0 = (ksl * HHH + h) * NN + q0;
    #pragma unroll
    for (int r = 0; r < 4; r++) {
        size_t ob = (size_t)(base0 + lg * 4 + r) * 32;
        po[ob + lc] = o0[r];
        po[ob + 16 + lc] = o1[r];
    }
    #pragma unroll
    for (int r = 0; r < 4; r++) {
        if (lc == r && lg >= 0) {
            pm[base0 + lg * 4 + r] = mx[r];
            pl[base0 + lg * 4 + r] = ls[r];
        }
    }
}

__global__ __launch_bounds__(256) void attn_comb(
    const float* __restrict__ po, const float* __restrict__ pm, const float* __restrict__ pl,
    float* __restrict__ o_at)
{
    int idx = blockIdx.x * 256 + threadIdx.x;  // N*128
    int n = idx >> 7, hc = idx & 127, hh = hc >> 5, c = idx & 31;
    float M = -1e30f;
    #pragma unroll
    for (int s = 0; s < KSLICES; s++) M = fmaxf(M, pm[(s * HHH + hh) * NN + n]);
    float accv = 0.f, L = 0.f;
    #pragma unroll
    for (int s = 0; s < KSLICES; s++) {
        int id = (s * HHH + hh) * NN + n;
        float wgt = __expf(pm[id] - M);
        L = fmaf(wgt, pl[id], L);
        accv = fmaf(wgt, po[(size_t)id * 32 + c], accv);
    }
    o_at[idx] = accv / L;
}

// ---------------- combine; final ----------------
__global__ __launch_bounds__(256) void combine_kernel(
    const float* __restrict__ y1, const float* __restrict__ y2,
    const float* __restrict__ stats,
    const float* __restrict__ g1, const float* __restrict__ be1,
    const float* __restrict__ g2, const float* __restrict__ be2,
    float* __restrict__ outp)
{
    int idx = blockIdx.x * 256 + threadIdx.x;
    int c = idx & 127;
    float v1 = (y1[idx] - stats[c]) * stats[128 + c] * g1[c] + be1[c];
    float v2 = (y2[idx] - stats[256 + c]) * stats[384 + c] * g2[c] + be2[c];
    outp[idx] = v1 + v2;
}

__global__ __launch_bounds__(256) void final_kernel(
    const float* __restrict__ out2, const float* __restrict__ stats,
    const float* __restrict__ g3, const float* __restrict__ be3,
    float* __restrict__ outv)
{
    int idx = blockIdx.x * 256 + threadIdx.x;
    int c = idx & 127;
    outv[idx] = (out2[idx] - stats[512 + c]) * stats[640 + c] * g3[c] + be3[c];
}

extern "C" void kernel_launch(void* const* d_in, const int* in_sizes, int n_in,
                              void* d_out, int out_size, void* d_ws, size_t ws_size,
                              hipStream_t stream)
{
    (void)in_sizes; (void)n_in; (void)out_size; (void)ws_size;
    const float* x_a   = (const float*)d_in[0];
    const float* x_b   = (const float*)d_in[1];
    const float* x_c   = (const float*)d_in[2];
    const int* ab_s    = (const int*)d_in[3];
    const int* ab_d    = (const int*)d_in[4];
    const int* ac_s    = (const int*)d_in[5];
    const int* ac_d    = (const int*)d_in[6];
    const int* cb_s    = (const int*)d_in[7];
    const int* cb_d    = (const int*)d_in[8];
    const float* W_in_a = (const float*)d_in[9];
    const float* b_in_a = (const float*)d_in[10];
    const float* W_in_b = (const float*)d_in[11];
    const float* b_in_b = (const float*)d_in[12];
    const float* W_in_c = (const float*)d_in[13];
    const float* b_in_c = (const float*)d_in[14];
    const float* W_gat  = (const float*)d_in[15];
    const float* att_src = (const float*)d_in[16];
    const float* att_dst = (const float*)d_in[17];
    const float* b_gat  = (const float*)d_in[18];
    const float* W_qkv  = (const float*)d_in[19];
    const float* b_qkv  = (const float*)d_in[20];
    const float* W_o    = (const float*)d_in[21];
    const float* b_o    = (const float*)d_in[22];
    const float* g1     = (const float*)d_in[23];
    const float* be1    = (const float*)d_in[24];
    const float* g2     = (const float*)d_in[25];
    const float* be2    = (const float*)d_in[26];
    const float* g3     = (const float*)d_in[27];
    const float* be3    = (const float*)d_in[28];
    const float* W_mlp1 = (const float*)d_in[29];
    const float* b_mlp1 = (const float*)d_in[30];
    const float* W_mlp2 = (const float*)d_in[31];
    const float* b_mlp2 = (const float*)d_in[32];

    float* ws   = (float*)d_ws;
    float* h    = ws + 0;          // 524288
    float* qkv  = ws + 524288;     // 1572864
    float* o_at = ws + 2097152;    // 524288
    float* y2   = ws + 2621440;    // 524288 (attn-time: pm/pl; later: o-proj+res)
    float* stats = ws + 3145728;   // 768
    float* R    = ws + 3146496;    // 4456448 floats (reused region)
    // attention-time views:
    float* po = R;                 // 4*4*4096*32 = 2097152 floats (fp32 unnormalized partial O)
    float* pm = y2;                // 65536
    float* pl = y2 + 65536;        // 65536
    // post-attention view of R:
    float* xp   = R + 0;           // 524288
    float* y1   = R + 524288;      // 524288
    float* outp = R + 1048576;     // 524288
    float* hid  = R + 1572864;     // 1048576
    float* out2 = R + 2621440;     // 524288
    float* asv  = R + 3145728;     // 16384
    float* adv  = R + 3162112;     // 16384
    int* cnt    = (int*)(R + 3178496);
    int* rowptr = cnt + 4096;      // 4104 incl pad
    int* fill   = rowptr + 4104;
    int* csr    = fill + 4096;     // E_TOT

    // ---- projections + qkv ----
    gemm_kernel<<<dim3(2, 32), 256, 0, stream>>>(x_a, W_in_a, b_in_a, nullptr, h, NA, 128, 128, 0, 0);
    gemm_kernel<<<dim3(2, 16), 256, 0, stream>>>(x_b, W_in_b, b_in_b, nullptr, h + (size_t)NA * 128, NB, 128, 128, 0, 0);
    gemm_kernel<<<dim3(2, 16), 256, 0, stream>>>(x_c, W_in_c, b_in_c, nullptr, h + (size_t)(NA + NB) * 128, NC, 128, 128, 0, 0);
    gemm_kernel<<<dim3(6, 64), 256, 0, stream>>>(h, W_qkv, b_qkv, nullptr, qkv, NN, 384, 128, 1, 0);
    // ---- global attention (MFMA flash) ----
    attn_kernel<<<256 * HHH * KSLICES, 64, 0, stream>>>(qkv, po, pm, pl);
    attn_comb<<<NN * 128 / 256, 256, 0, stream>>>(po, pm, pl, o_at);
    gemm_kernel<<<dim3(2, 64), 256, 0, stream>>>(o_at, W_o, b_o, h, y2, NN, 128, 128, 1, 0);
    bn_stats<<<128, 256, 0, stream>>>(y2, stats + 256, stats + 384);
    // ---- GAT branch (R reused) ----
    gemm_kernel<<<dim3(2, 64), 256, 0, stream>>>(h, W_gat, nullptr, nullptr, xp, NN, 128, 128, 0, 0);
    att_scores<<<64, 256, 0, stream>>>(xp, att_src, att_dst, asv, adv);
    hipMemsetAsync(cnt, 0, NN * sizeof(int), stream);
    edge_hist<<<E_TOT / 256, 256, 0, stream>>>(ab_d, ac_d, cb_d, cnt);
    scan_kernel<<<1, 256, 0, stream>>>(cnt, rowptr, fill);
    edge_scatter<<<E_TOT / 256, 256, 0, stream>>>(ab_s, ab_d, ac_s, ac_d, cb_s, cb_d, fill, csr);
    gat_gather<<<NN, 128, 0, stream>>>(xp, asv, adv, rowptr, csr, b_gat, h, y1);
    bn_stats<<<128, 256, 0, stream>>>(y1, stats + 0, stats + 128);
    // ---- combine + MLP ----
    combine_kernel<<<NN * 128 / 256, 256, 0, stream>>>(y1, y2, stats, g1, be1, g2, be2, outp);
    gemm_kernel<<<dim3(4, 64), 256, 0, stream>>>(outp, W_mlp1, b_mlp1, nullptr, hid, NN, 256, 128, 0, 1);
    gemm_kernel<<<dim3(2, 64), 256, 0, stream>>>(hid, W_mlp2, b_mlp2, outp, out2, NN, 128, 256, 0, 0);
    bn_stats<<<128, 256, 0, stream>>>(out2, stats + 512, stats + 640);
    final_kernel<<<NN * 128 / 256, 256, 0, stream>>>(out2, stats, g3, be3, (float*)d_out);
}